// Round 2
// baseline (322.682 us; speedup 1.0000x reference)
//
#include <hip/hip_runtime.h>
#include <cstddef>

#define F 128
#define BM 64
#define LDT 132  // padded LDS stride (floats) for the x/hid tile

__device__ __forceinline__ float f4c(const float4& v, int i) {
  return i == 0 ? v.x : (i == 1 ? v.y : (i == 2 ? v.z : v.w));
}

// ---------------- Hamilton build ----------------
// hamilton[rb*32+p][cb*32+c] = sign * kernel[p][(rb^cb)*32 + c]
// negative-sign bitmask per (cb,rb): 0x284E
__global__ __launch_bounds__(256) void build_hamilton(
    const float* __restrict__ w1, const float* __restrict__ w2,
    float* __restrict__ H1, float* __restrict__ H2) {
  int idx = blockIdx.x * 256 + threadIdx.x;  // 0..32767 (2 matrices)
  int m = idx >> 14;
  int rem = idx & 16383;
  int row = rem >> 7;
  int col = rem & 127;
  int rb = row >> 5, p = row & 31;
  int cb = col >> 5, c = col & 31;
  int comp = rb ^ cb;
  int neg = (0x284E >> (cb * 4 + rb)) & 1;
  const float* w = m ? w2 : w1;
  float v = w[p * 128 + comp * 32 + c];
  float* H = m ? H2 : H1;
  H[row * 128 + col] = neg ? -v : v;
}

// ---------------- fused GEMM: out2 = tanh(X @ H1) @ H2 ----------------
#define FMA8(ri, XV)                              \
  acc[ri][0] = fmaf(XV, b0.x, acc[ri][0]);        \
  acc[ri][1] = fmaf(XV, b0.y, acc[ri][1]);        \
  acc[ri][2] = fmaf(XV, b0.z, acc[ri][2]);        \
  acc[ri][3] = fmaf(XV, b0.w, acc[ri][3]);        \
  acc[ri][4] = fmaf(XV, b1.x, acc[ri][4]);        \
  acc[ri][5] = fmaf(XV, b1.y, acc[ri][5]);        \
  acc[ri][6] = fmaf(XV, b1.z, acc[ri][6]);        \
  acc[ri][7] = fmaf(XV, b1.w, acc[ri][7]);

__global__ __launch_bounds__(256) void gemm_fused(
    const float* __restrict__ input, const float* __restrict__ H1f,
    const float* __restrict__ H2f, float* __restrict__ out2, int N) {
  __shared__ float Hs[F * F];      // 64 KB, reused H1 -> H2
  __shared__ float xs[BM * LDT];   // input tile, then hid tile (aliased)
  const int t = threadIdx.x;
  const int r0g = blockIdx.x * BM;
  const int c0 = (t & 15) * 8;
  const int r0 = (t >> 4) * 4;

  // stage H1
#pragma unroll
  for (int i = 0; i < 16; ++i) {
    int fi = (i * 256 + t) * 4;
    *(float4*)&Hs[fi] = *(const float4*)&H1f[fi];
  }
  // stage input tile (zero-pad rows >= N)
#pragma unroll
  for (int i = 0; i < 8; ++i) {
    int idx4 = i * 256 + t;
    int row = idx4 >> 5;
    int c4 = (idx4 & 31) * 4;
    int grow = r0g + row;
    float4 v = make_float4(0.f, 0.f, 0.f, 0.f);
    if (grow < N) v = *(const float4*)&input[(size_t)grow * F + c4];
    *(float4*)&xs[row * LDT + c4] = v;
  }
  __syncthreads();

  float acc[4][8];
#pragma unroll
  for (int ri = 0; ri < 4; ++ri)
#pragma unroll
    for (int ci = 0; ci < 8; ++ci) acc[ri][ci] = 0.f;

  // phase A: acc = X @ H1
#pragma unroll 2
  for (int k = 0; k < F; k += 4) {
    float4 a0 = *(const float4*)&xs[(r0 + 0) * LDT + k];
    float4 a1 = *(const float4*)&xs[(r0 + 1) * LDT + k];
    float4 a2 = *(const float4*)&xs[(r0 + 2) * LDT + k];
    float4 a3 = *(const float4*)&xs[(r0 + 3) * LDT + k];
#pragma unroll
    for (int kk = 0; kk < 4; ++kk) {
      float4 b0 = *(const float4*)&Hs[(k + kk) * F + c0];
      float4 b1 = *(const float4*)&Hs[(k + kk) * F + c0 + 4];
      float x0 = f4c(a0, kk), x1 = f4c(a1, kk), x2 = f4c(a2, kk), x3 = f4c(a3, kk);
      FMA8(0, x0)
      FMA8(1, x1)
      FMA8(2, x2)
      FMA8(3, x3)
    }
  }
  __syncthreads();  // everyone done reading xs (X) and Hs (H1)

  // hid = tanh(acc) -> xs ; stage H2 -> Hs
#pragma unroll
  for (int ri = 0; ri < 4; ++ri) {
    float4 h0, h1;
    h0.x = tanhf(acc[ri][0]); h0.y = tanhf(acc[ri][1]);
    h0.z = tanhf(acc[ri][2]); h0.w = tanhf(acc[ri][3]);
    h1.x = tanhf(acc[ri][4]); h1.y = tanhf(acc[ri][5]);
    h1.z = tanhf(acc[ri][6]); h1.w = tanhf(acc[ri][7]);
    *(float4*)&xs[(r0 + ri) * LDT + c0] = h0;
    *(float4*)&xs[(r0 + ri) * LDT + c0 + 4] = h1;
  }
#pragma unroll
  for (int i = 0; i < 16; ++i) {
    int fi = (i * 256 + t) * 4;
    *(float4*)&Hs[fi] = *(const float4*)&H2f[fi];
  }
  __syncthreads();

  // phase B: acc = hid @ H2
#pragma unroll
  for (int ri = 0; ri < 4; ++ri)
#pragma unroll
    for (int ci = 0; ci < 8; ++ci) acc[ri][ci] = 0.f;

#pragma unroll 2
  for (int k = 0; k < F; k += 4) {
    float4 a0 = *(const float4*)&xs[(r0 + 0) * LDT + k];
    float4 a1 = *(const float4*)&xs[(r0 + 1) * LDT + k];
    float4 a2 = *(const float4*)&xs[(r0 + 2) * LDT + k];
    float4 a3 = *(const float4*)&xs[(r0 + 3) * LDT + k];
#pragma unroll
    for (int kk = 0; kk < 4; ++kk) {
      float4 b0 = *(const float4*)&Hs[(k + kk) * F + c0];
      float4 b1 = *(const float4*)&Hs[(k + kk) * F + c0 + 4];
      float x0 = f4c(a0, kk), x1 = f4c(a1, kk), x2 = f4c(a2, kk), x3 = f4c(a3, kk);
      FMA8(0, x0)
      FMA8(1, x1)
      FMA8(2, x2)
      FMA8(3, x3)
    }
  }

  // store out2
#pragma unroll
  for (int ri = 0; ri < 4; ++ri) {
    int grow = r0g + r0 + ri;
    if (grow < N) {
      float4 v0 = make_float4(acc[ri][0], acc[ri][1], acc[ri][2], acc[ri][3]);
      float4 v1 = make_float4(acc[ri][4], acc[ri][5], acc[ri][6], acc[ri][7]);
      *(float4*)&out2[(size_t)grow * F + c0] = v0;
      *(float4*)&out2[(size_t)grow * F + c0 + 4] = v1;
    }
  }
}

// ---------------- segment-sum SpMM: agg[i] = sum_e val[e]*out2[col[e]] ----------------
__global__ __launch_bounds__(128) void agg_rows(
    const float* __restrict__ out2, const int* __restrict__ adj_row,
    const int* __restrict__ adj_col, const float* __restrict__ adj_val,
    float* __restrict__ agg, int E) {
  const int row = blockIdx.x;
  const int f = threadIdx.x;
  // adj_row is sorted: binary-search this row's segment (uniform across block)
  int lo = 0, hi = E;
  while (lo < hi) { int mid = (lo + hi) >> 1; if (adj_row[mid] < row) lo = mid + 1; else hi = mid; }
  const int start = lo;
  hi = E;
  while (lo < hi) { int mid = (lo + hi) >> 1; if (adj_row[mid] <= row) lo = mid + 1; else hi = mid; }
  const int end = lo;
  float acc = 0.f;
  for (int e = start; e < end; ++e) {
    acc = fmaf(adj_val[e], out2[(size_t)adj_col[e] * F + f], acc);
  }
  agg[(size_t)row * F + f] = acc;
}

// ---------------- BN stats: per-feature sum & sumsq ----------------
__global__ __launch_bounds__(256) void reduce_stats(
    const float* __restrict__ agg, float* __restrict__ sumbuf, int N) {
  const int t = threadIdx.x;
  const int f4 = t & 31;   // float4 column
  const int rl = t >> 5;   // 0..7
  const int rpb = (N + gridDim.x - 1) / gridDim.x;
  const int r0 = blockIdx.x * rpb;
  const int r1 = min(N, r0 + rpb);
  float s0 = 0, s1 = 0, s2 = 0, s3 = 0, q0 = 0, q1 = 0, q2 = 0, q3 = 0;
  for (int r = r0 + rl; r < r1; r += 8) {
    float4 v = *(const float4*)&agg[(size_t)r * F + f4 * 4];
    s0 += v.x; s1 += v.y; s2 += v.z; s3 += v.w;
    q0 = fmaf(v.x, v.x, q0); q1 = fmaf(v.y, v.y, q1);
    q2 = fmaf(v.z, v.z, q2); q3 = fmaf(v.w, v.w, q3);
  }
  __shared__ float ls[256][4];
  __shared__ float lq[256][4];
  ls[t][0] = s0; ls[t][1] = s1; ls[t][2] = s2; ls[t][3] = s3;
  lq[t][0] = q0; lq[t][1] = q1; lq[t][2] = q2; lq[t][3] = q3;
  __syncthreads();
  if (t < 32) {
    float S[4] = {0, 0, 0, 0}, Q[4] = {0, 0, 0, 0};
#pragma unroll
    for (int g = 0; g < 8; ++g)
#pragma unroll
      for (int j = 0; j < 4; ++j) {
        S[j] += ls[t + 32 * g][j];
        Q[j] += lq[t + 32 * g][j];
      }
#pragma unroll
    for (int j = 0; j < 4; ++j) {
      atomicAdd(&sumbuf[t * 4 + j], S[j]);
      atomicAdd(&sumbuf[128 + t * 4 + j], Q[j]);
    }
  }
}

__global__ void finalize_stats(const float* __restrict__ sumbuf,
                               const float* __restrict__ gamma,
                               const float* __restrict__ beta,
                               float* __restrict__ ss, float invN) {
  int f = threadIdx.x;  // 128
  float mean = sumbuf[f] * invN;
  float var = sumbuf[128 + f] * invN - mean * mean;
  float inv = rsqrtf(var + 1e-5f);
  float sc = gamma[f] * inv;
  ss[f] = sc;
  ss[128 + f] = beta[f] - mean * sc;
}

__global__ __launch_bounds__(256) void bn_apply(
    float* __restrict__ out, const float* __restrict__ ss, int total4) {
  int idx = blockIdx.x * 256 + threadIdx.x;
  if (idx >= total4) return;
  int f4 = (idx & 31) * 4;
  float4 v = *(float4*)&out[(size_t)idx * 4];
  float4 sc = *(const float4*)&ss[f4];
  float4 sh = *(const float4*)&ss[128 + f4];
  v.x = fmaf(v.x, sc.x, sh.x);
  v.y = fmaf(v.y, sc.y, sh.y);
  v.z = fmaf(v.z, sc.z, sh.z);
  v.w = fmaf(v.w, sc.w, sh.w);
  *(float4*)&out[(size_t)idx * 4] = v;
}

// ---------------- launch ----------------
// ws layout (floats):
//   [0,16384)      H1
//   [16384,32768)  H2
//   [32768,33024)  sumbuf: sum[128], sumsq[128]   (memset each call)
//   [33024,33280)  ss: scale[128], shift[128]
//   [33280,...)    out2 [N*128]
extern "C" void kernel_launch(void* const* d_in, const int* in_sizes, int n_in,
                              void* d_out, int out_size, void* d_ws, size_t ws_size,
                              hipStream_t stream) {
  (void)n_in; (void)out_size; (void)ws_size;
  const float* input  = (const float*)d_in[0];
  const int*  adj_row = (const int*)d_in[1];
  const int*  adj_col = (const int*)d_in[2];
  const float* adj_val = (const float*)d_in[3];
  const float* w1 = (const float*)d_in[4];
  const float* w2 = (const float*)d_in[5];
  const float* gamma = (const float*)d_in[6];
  const float* beta  = (const float*)d_in[7];
  const int N = in_sizes[0] / F;
  const int E = in_sizes[1];

  float* ws = (float*)d_ws;
  float* H1 = ws;
  float* H2 = ws + 16384;
  float* sumbuf = ws + 32768;
  float* ss = ws + 33024;
  float* out2 = ws + 33280;
  float* agg = (float*)d_out;

  (void)hipMemsetAsync(sumbuf, 0, 256 * sizeof(float), stream);
  build_hamilton<<<128, 256, 0, stream>>>(w1, w2, H1, H2);
  gemm_fused<<<(N + BM - 1) / BM, 256, 0, stream>>>(input, H1, H2, out2, N);
  agg_rows<<<N, 128, 0, stream>>>(out2, adj_row, adj_col, adj_val, agg, E);
  reduce_stats<<<512, 256, 0, stream>>>(agg, sumbuf, N);
  finalize_stats<<<1, 128, 0, stream>>>(sumbuf, gamma, beta, ss, 1.0f / (float)N);
  bn_apply<<<(N * 32 + 255) / 256, 256, 0, stream>>>(agg, ss, N * 32);
}

// Round 3
// 196.292 us; speedup vs baseline: 1.6439x; 1.6439x over previous
//
#include <hip/hip_runtime.h>
#include <cstddef>
#include <cstdint>

#define F 128
#define BM 64
#define LDT 132  // padded LDS stride (floats) for the x/hid tile

typedef __attribute__((ext_vector_type(8))) short short8;

__device__ __forceinline__ float f4c(const float4& v, int i) {
  return i == 0 ? v.x : (i == 1 ? v.y : (i == 2 ? v.z : v.w));
}

__device__ __forceinline__ short f2bf(float f) {
  uint32_t u = __float_as_uint(f);
  uint32_t r = u + 0x7FFFu + ((u >> 16) & 1u);  // round-to-nearest-even
  return (short)(r >> 16);
}

// ---------------- Hamilton build ----------------
// hamilton[rb*32+p][cb*32+c] = sign * kernel[p][(rb^cb)*32 + c]
// negative-sign bitmask per (cb,rb): 0x284E
__global__ __launch_bounds__(256) void build_hamilton(
    const float* __restrict__ w1, const float* __restrict__ w2,
    float* __restrict__ H1, float* __restrict__ H2) {
  int idx = blockIdx.x * 256 + threadIdx.x;  // 0..32767 (2 matrices)
  int m = idx >> 14;
  int rem = idx & 16383;
  int row = rem >> 7;
  int col = rem & 127;
  int rb = row >> 5, p = row & 31;
  int cb = col >> 5, c = col & 31;
  int comp = rb ^ cb;
  int neg = (0x284E >> (cb * 4 + rb)) & 1;
  const float* w = m ? w2 : w1;
  float v = w[p * 128 + comp * 32 + c];
  float* H = m ? H2 : H1;
  H[row * 128 + col] = neg ? -v : v;
}

// ---------------- fused GEMM: out2 = tanh(X @ H1) @ H2, stored bf16 ----------------
#define FMA8(ri, XV)                              \
  acc[ri][0] = fmaf(XV, b0.x, acc[ri][0]);        \
  acc[ri][1] = fmaf(XV, b0.y, acc[ri][1]);        \
  acc[ri][2] = fmaf(XV, b0.z, acc[ri][2]);        \
  acc[ri][3] = fmaf(XV, b0.w, acc[ri][3]);        \
  acc[ri][4] = fmaf(XV, b1.x, acc[ri][4]);        \
  acc[ri][5] = fmaf(XV, b1.y, acc[ri][5]);        \
  acc[ri][6] = fmaf(XV, b1.z, acc[ri][6]);        \
  acc[ri][7] = fmaf(XV, b1.w, acc[ri][7]);

__global__ __launch_bounds__(256) void gemm_fused(
    const float* __restrict__ input, const float* __restrict__ H1f,
    const float* __restrict__ H2f, short* __restrict__ out2b, int N) {
  __shared__ float Hs[F * F];      // 64 KB, reused H1 -> H2
  __shared__ float xs[BM * LDT];   // input tile, then hid tile (aliased)
  const int t = threadIdx.x;
  const int r0g = blockIdx.x * BM;
  const int c0 = (t & 15) * 8;
  const int r0 = (t >> 4) * 4;

  // stage H1
#pragma unroll
  for (int i = 0; i < 16; ++i) {
    int fi = (i * 256 + t) * 4;
    *(float4*)&Hs[fi] = *(const float4*)&H1f[fi];
  }
  // stage input tile (zero-pad rows >= N)
#pragma unroll
  for (int i = 0; i < 8; ++i) {
    int idx4 = i * 256 + t;
    int row = idx4 >> 5;
    int c4 = (idx4 & 31) * 4;
    int grow = r0g + row;
    float4 v = make_float4(0.f, 0.f, 0.f, 0.f);
    if (grow < N) v = *(const float4*)&input[(size_t)grow * F + c4];
    *(float4*)&xs[row * LDT + c4] = v;
  }
  __syncthreads();

  float acc[4][8];
#pragma unroll
  for (int ri = 0; ri < 4; ++ri)
#pragma unroll
    for (int ci = 0; ci < 8; ++ci) acc[ri][ci] = 0.f;

  // phase A: acc = X @ H1
#pragma unroll 2
  for (int k = 0; k < F; k += 4) {
    float4 a0 = *(const float4*)&xs[(r0 + 0) * LDT + k];
    float4 a1 = *(const float4*)&xs[(r0 + 1) * LDT + k];
    float4 a2 = *(const float4*)&xs[(r0 + 2) * LDT + k];
    float4 a3 = *(const float4*)&xs[(r0 + 3) * LDT + k];
#pragma unroll
    for (int kk = 0; kk < 4; ++kk) {
      float4 b0 = *(const float4*)&Hs[(k + kk) * F + c0];
      float4 b1 = *(const float4*)&Hs[(k + kk) * F + c0 + 4];
      float x0 = f4c(a0, kk), x1 = f4c(a1, kk), x2 = f4c(a2, kk), x3 = f4c(a3, kk);
      FMA8(0, x0)
      FMA8(1, x1)
      FMA8(2, x2)
      FMA8(3, x3)
    }
  }
  __syncthreads();  // everyone done reading xs (X) and Hs (H1)

  // hid = tanh(acc) -> xs ; stage H2 -> Hs
#pragma unroll
  for (int ri = 0; ri < 4; ++ri) {
    float4 h0, h1;
    h0.x = tanhf(acc[ri][0]); h0.y = tanhf(acc[ri][1]);
    h0.z = tanhf(acc[ri][2]); h0.w = tanhf(acc[ri][3]);
    h1.x = tanhf(acc[ri][4]); h1.y = tanhf(acc[ri][5]);
    h1.z = tanhf(acc[ri][6]); h1.w = tanhf(acc[ri][7]);
    *(float4*)&xs[(r0 + ri) * LDT + c0] = h0;
    *(float4*)&xs[(r0 + ri) * LDT + c0 + 4] = h1;
  }
#pragma unroll
  for (int i = 0; i < 16; ++i) {
    int fi = (i * 256 + t) * 4;
    *(float4*)&Hs[fi] = *(const float4*)&H2f[fi];
  }
  __syncthreads();

  // phase B: acc = hid @ H2
#pragma unroll
  for (int ri = 0; ri < 4; ++ri)
#pragma unroll
    for (int ci = 0; ci < 8; ++ci) acc[ri][ci] = 0.f;

#pragma unroll 2
  for (int k = 0; k < F; k += 4) {
    float4 a0 = *(const float4*)&xs[(r0 + 0) * LDT + k];
    float4 a1 = *(const float4*)&xs[(r0 + 1) * LDT + k];
    float4 a2 = *(const float4*)&xs[(r0 + 2) * LDT + k];
    float4 a3 = *(const float4*)&xs[(r0 + 3) * LDT + k];
#pragma unroll
    for (int kk = 0; kk < 4; ++kk) {
      float4 b0 = *(const float4*)&Hs[(k + kk) * F + c0];
      float4 b1 = *(const float4*)&Hs[(k + kk) * F + c0 + 4];
      float x0 = f4c(a0, kk), x1 = f4c(a1, kk), x2 = f4c(a2, kk), x3 = f4c(a3, kk);
      FMA8(0, x0)
      FMA8(1, x1)
      FMA8(2, x2)
      FMA8(3, x3)
    }
  }

  // store out2 as bf16 (8 per thread-row = 16B stores)
#pragma unroll
  for (int ri = 0; ri < 4; ++ri) {
    int grow = r0g + r0 + ri;
    if (grow < N) {
      short8 pk;
#pragma unroll
      for (int ci = 0; ci < 8; ++ci) pk[ci] = f2bf(acc[ri][ci]);
      *(short8*)&out2b[(size_t)grow * F + c0] = pk;
    }
  }
}

// ---------------- CSR rowptr from sorted adj_row ----------------
__global__ __launch_bounds__(256) void build_rowptr(
    const int* __restrict__ adj_row, int* __restrict__ rowptr, int E, int N) {
  int e = blockIdx.x * 256 + threadIdx.x;
  if (e >= E) return;
  int r = adj_row[e];
  int rprev = (e == 0) ? -1 : adj_row[e - 1];
  for (int q = rprev + 1; q <= r; ++q) rowptr[q] = e;
  if (e == E - 1) {
    for (int q = r + 1; q <= N; ++q) rowptr[q] = E;
  }
}

// ---------------- segment-sum SpMM: wave per row, bf16 gather ----------------
__global__ __launch_bounds__(256) void agg_rows2(
    const uint32_t* __restrict__ out2u,  // N x 64 uints (bf16 pairs)
    const int* __restrict__ rowptr, const int* __restrict__ adj_col,
    const float* __restrict__ adj_val, float* __restrict__ agg, int N) {
  int gw = (blockIdx.x * 256 + threadIdx.x) >> 6;
  const int lane = threadIdx.x & 63;
  if (gw >= N) return;
  const int row = __builtin_amdgcn_readfirstlane(gw);  // wave-uniform -> SGPR
  int e = rowptr[row];
  const int end = rowptr[row + 1];
  float accx = 0.f, accy = 0.f;

  for (; e + 8 <= end; e += 8) {
    int c[8]; float v[8]; uint32_t u[8];
#pragma unroll
    for (int j = 0; j < 8; ++j) { c[j] = adj_col[e + j]; v[j] = adj_val[e + j]; }
#pragma unroll
    for (int j = 0; j < 8; ++j) u[j] = out2u[(size_t)c[j] * 64 + lane];
#pragma unroll
    for (int j = 0; j < 8; ++j) {
      accx = fmaf(v[j], __uint_as_float(u[j] << 16), accx);
      accy = fmaf(v[j], __uint_as_float(u[j] & 0xFFFF0000u), accy);
    }
  }
  for (; e + 2 <= end; e += 2) {
    int c0 = adj_col[e], c1 = adj_col[e + 1];
    float v0 = adj_val[e], v1 = adj_val[e + 1];
    uint32_t u0 = out2u[(size_t)c0 * 64 + lane];
    uint32_t u1 = out2u[(size_t)c1 * 64 + lane];
    accx = fmaf(v0, __uint_as_float(u0 << 16), accx);
    accy = fmaf(v0, __uint_as_float(u0 & 0xFFFF0000u), accy);
    accx = fmaf(v1, __uint_as_float(u1 << 16), accx);
    accy = fmaf(v1, __uint_as_float(u1 & 0xFFFF0000u), accy);
  }
  if (e < end) {
    int c0 = adj_col[e];
    float v0 = adj_val[e];
    uint32_t u0 = out2u[(size_t)c0 * 64 + lane];
    accx = fmaf(v0, __uint_as_float(u0 << 16), accx);
    accy = fmaf(v0, __uint_as_float(u0 & 0xFFFF0000u), accy);
  }
  *(float2*)&agg[(size_t)row * F + lane * 2] = make_float2(accx, accy);
}

// ---------------- BN stats: per-feature sum & sumsq ----------------
__global__ __launch_bounds__(256) void reduce_stats(
    const float* __restrict__ agg, float* __restrict__ sumbuf, int N) {
  const int t = threadIdx.x;
  const int f4 = t & 31;   // float4 column
  const int rl = t >> 5;   // 0..7
  const int rpb = (N + gridDim.x - 1) / gridDim.x;
  const int r0 = blockIdx.x * rpb;
  const int r1 = min(N, r0 + rpb);
  float s0 = 0, s1 = 0, s2 = 0, s3 = 0, q0 = 0, q1 = 0, q2 = 0, q3 = 0;
  for (int r = r0 + rl; r < r1; r += 8) {
    float4 v = *(const float4*)&agg[(size_t)r * F + f4 * 4];
    s0 += v.x; s1 += v.y; s2 += v.z; s3 += v.w;
    q0 = fmaf(v.x, v.x, q0); q1 = fmaf(v.y, v.y, q1);
    q2 = fmaf(v.z, v.z, q2); q3 = fmaf(v.w, v.w, q3);
  }
  __shared__ float ls[256][4];
  __shared__ float lq[256][4];
  ls[t][0] = s0; ls[t][1] = s1; ls[t][2] = s2; ls[t][3] = s3;
  lq[t][0] = q0; lq[t][1] = q1; lq[t][2] = q2; lq[t][3] = q3;
  __syncthreads();
  if (t < 32) {
    float S[4] = {0, 0, 0, 0}, Q[4] = {0, 0, 0, 0};
#pragma unroll
    for (int g = 0; g < 8; ++g)
#pragma unroll
      for (int j = 0; j < 4; ++j) {
        S[j] += ls[t + 32 * g][j];
        Q[j] += lq[t + 32 * g][j];
      }
#pragma unroll
    for (int j = 0; j < 4; ++j) {
      atomicAdd(&sumbuf[t * 4 + j], S[j]);
      atomicAdd(&sumbuf[128 + t * 4 + j], Q[j]);
    }
  }
}

__global__ void finalize_stats(const float* __restrict__ sumbuf,
                               const float* __restrict__ gamma,
                               const float* __restrict__ beta,
                               float* __restrict__ ss, float invN) {
  int f = threadIdx.x;  // 128
  float mean = sumbuf[f] * invN;
  float var = sumbuf[128 + f] * invN - mean * mean;
  float inv = rsqrtf(var + 1e-5f);
  float sc = gamma[f] * inv;
  ss[f] = sc;
  ss[128 + f] = beta[f] - mean * sc;
}

__global__ __launch_bounds__(256) void bn_apply(
    float* __restrict__ out, const float* __restrict__ ss, int total4) {
  int idx = blockIdx.x * 256 + threadIdx.x;
  if (idx >= total4) return;
  int f4 = (idx & 31) * 4;
  float4 v = *(float4*)&out[(size_t)idx * 4];
  float4 sc = *(const float4*)&ss[f4];
  float4 sh = *(const float4*)&ss[128 + f4];
  v.x = fmaf(v.x, sc.x, sh.x);
  v.y = fmaf(v.y, sc.y, sh.y);
  v.z = fmaf(v.z, sc.z, sh.z);
  v.w = fmaf(v.w, sc.w, sh.w);
  *(float4*)&out[(size_t)idx * 4] = v;
}

// ---------------- launch ----------------
// ws layout (bytes):
//   [0,        65536)   H1 (fp32 128x128)
//   [65536,   131072)   H2
//   [131072,  132096)   sumbuf: sum[128], sumsq[128]  (memset each call)
//   [132096,  133120)   ss: scale[128], shift[128]
//   [133120,  337920)   rowptr (N+1 ints, padded)
//   [337920,  ...)      out2 bf16 [N*128]
extern "C" void kernel_launch(void* const* d_in, const int* in_sizes, int n_in,
                              void* d_out, int out_size, void* d_ws, size_t ws_size,
                              hipStream_t stream) {
  (void)n_in; (void)out_size; (void)ws_size;
  const float* input  = (const float*)d_in[0];
  const int*  adj_row = (const int*)d_in[1];
  const int*  adj_col = (const int*)d_in[2];
  const float* adj_val = (const float*)d_in[3];
  const float* w1 = (const float*)d_in[4];
  const float* w2 = (const float*)d_in[5];
  const float* gamma = (const float*)d_in[6];
  const float* beta  = (const float*)d_in[7];
  const int N = in_sizes[0] / F;
  const int E = in_sizes[1];

  char* ws = (char*)d_ws;
  float* H1 = (float*)(ws);
  float* H2 = (float*)(ws + 65536);
  float* sumbuf = (float*)(ws + 131072);
  float* ss = (float*)(ws + 132096);
  int* rowptr = (int*)(ws + 133120);
  short* out2b = (short*)(ws + 337920);
  float* agg = (float*)d_out;

  (void)hipMemsetAsync(sumbuf, 0, 256 * sizeof(float), stream);
  build_hamilton<<<128, 256, 0, stream>>>(w1, w2, H1, H2);
  gemm_fused<<<(N + BM - 1) / BM, 256, 0, stream>>>(input, H1, H2, out2b, N);
  build_rowptr<<<(E + 255) / 256, 256, 0, stream>>>(adj_row, rowptr, E, N);
  agg_rows2<<<(N * 64 + 255) / 256, 256, 0, stream>>>(
      (const uint32_t*)out2b, rowptr, adj_col, adj_val, agg, N);
  reduce_stats<<<512, 256, 0, stream>>>(agg, sumbuf, N);
  finalize_stats<<<1, 128, 0, stream>>>(sumbuf, gamma, beta, ss, 1.0f / (float)N);
  bn_apply<<<(N * 32 + 255) / 256, 256, 0, stream>>>(agg, ss, N * 32);
}

// Round 4
// 144.992 us; speedup vs baseline: 2.2255x; 1.3538x over previous
//
#include <hip/hip_runtime.h>
#include <cstddef>
#include <cstdint>

#define F 128
#define LDH 20  // padded col stride (shorts) for per-wave LDS; keeps 8B align

typedef __attribute__((ext_vector_type(8))) short short8;
typedef __attribute__((ext_vector_type(4))) short short4v;
typedef __attribute__((ext_vector_type(4))) float f32x4;

__device__ __forceinline__ short f2bf(float f) {
  uint32_t u = __float_as_uint(f);
  uint32_t r = u + 0x7FFFu + ((u >> 16) & 1u);  // round-to-nearest-even
  return (short)(r >> 16);
}
__device__ __forceinline__ float bf2f(short h) {
  return __uint_as_float(((uint32_t)(uint16_t)h) << 16);
}

// ---------------- Hamilton build, packed in MFMA B-fragment order ----------------
// H[row][col] = sign * w[row&31][( (row>>5)^(col>>5) )*32 + (col&31)], neg mask 0x284E
// Hpk layout: [m(2)][part(2: hi,lo)][kt(4)][ct(8)][lane(64)][j(8)]
// B-frag: lane l, elem j  <->  B[kt*32 + (l>>4)*8 + j][ct*16 + (l&15)]
__global__ __launch_bounds__(256) void build_hpk(
    const float* __restrict__ w1, const float* __restrict__ w2,
    short* __restrict__ Hpk) {
  int idx = blockIdx.x * 256 + threadIdx.x;  // 4096: (m,kt,ct,lane)
  int m = idx >> 11;
  int kt = (idx >> 9) & 3;
  int ct = (idx >> 6) & 7;
  int l = idx & 63;
  int col = ct * 16 + (l & 15);
  const float* w = m ? w2 : w1;
  short hi[8], lo[8];
#pragma unroll
  for (int j = 0; j < 8; ++j) {
    int row = kt * 32 + (l >> 4) * 8 + j;  // k index of B
    int rb = row >> 5, cb = col >> 5;
    int neg = (0x284E >> (cb * 4 + rb)) & 1;
    float v = w[(row & 31) * 128 + (rb ^ cb) * 32 + (col & 31)];
    v = neg ? -v : v;
    short h = f2bf(v);
    hi[j] = h;
    lo[j] = f2bf(v - bf2f(h));
  }
  size_t b0 = ((((size_t)m * 2 + 0) * 4 + kt) * 8 + ct) * 64 + l;
  size_t b1 = ((((size_t)m * 2 + 1) * 4 + kt) * 8 + ct) * 64 + l;
  *(short8*)&Hpk[b0 * 8] = *(short8*)hi;
  *(short8*)&Hpk[b1 * 8] = *(short8*)lo;
}

// ---------------- fused MFMA GEMM: out2 = tanh(X @ H1) @ H2, bf16 out ----------------
// wave-per-16-rows, split-bf16 (hi/lo) operands, 3 mfma per tile, no barriers.
__global__ __launch_bounds__(256) void gemm_mfma(
    const float* __restrict__ input, const short* __restrict__ Hpk,
    short* __restrict__ out2b, int N) {
  __shared__ short lds[4][2][F * LDH];  // per-wave hi/lo hid tiles (40 KB)
  const int t = threadIdx.x;
  const int w = t >> 6, l = t & 63;
  const int lr = l & 15, lg = l >> 4;
  const int grow0 = blockIdx.x * 64 + w * 16;
  short* hidh = &lds[w][0][0];
  short* hidl = &lds[w][1][0];

  // A1 fragments from global f32, hi/lo split
  short8 a1h[4], a1l[4];
  {
    int arow = grow0 + lr;
    if (arow >= N) arow = N - 1;
    const float* xr = &input[(size_t)arow * F];
#pragma unroll
    for (int kt = 0; kt < 4; ++kt) {
      float xv[8];
      *(float4*)&xv[0] = *(const float4*)&xr[kt * 32 + lg * 8];
      *(float4*)&xv[4] = *(const float4*)&xr[kt * 32 + lg * 8 + 4];
#pragma unroll
      for (int j = 0; j < 8; ++j) {
        short h = f2bf(xv[j]);
        ((short*)&a1h[kt])[j] = h;
        ((short*)&a1l[kt])[j] = f2bf(xv[j] - bf2f(h));
      }
    }
  }

  // GEMM1: acc = X @ H1
  f32x4 acc[8];
#pragma unroll
  for (int ct = 0; ct < 8; ++ct) acc[ct] = (f32x4){0.f, 0.f, 0.f, 0.f};
#pragma unroll
  for (int kt = 0; kt < 4; ++kt) {
#pragma unroll
    for (int ct = 0; ct < 8; ++ct) {
      short8 bh = *(const short8*)&Hpk[((((size_t)0 * 4 + kt) * 8 + ct) * 64 + l) * 8];
      short8 bl = *(const short8*)&Hpk[((((size_t)1 * 4 + kt) * 8 + ct) * 64 + l) * 8];
      acc[ct] = __builtin_amdgcn_mfma_f32_16x16x32_bf16(a1l[kt], bh, acc[ct], 0, 0, 0);
      acc[ct] = __builtin_amdgcn_mfma_f32_16x16x32_bf16(a1h[kt], bl, acc[ct], 0, 0, 0);
      acc[ct] = __builtin_amdgcn_mfma_f32_16x16x32_bf16(a1h[kt], bh, acc[ct], 0, 0, 0);
    }
  }

  // hid = tanh(acc), split hi/lo, store col-major to per-wave LDS
  // C layout: col = ct*16 + lr, row = lg*4 + r
#pragma unroll
  for (int ct = 0; ct < 8; ++ct) {
    short hv[4], lv[4];
#pragma unroll
    for (int r = 0; r < 4; ++r) {
      float th = tanhf(acc[ct][r]);
      short h = f2bf(th);
      hv[r] = h;
      lv[r] = f2bf(th - bf2f(h));
    }
    int col = ct * 16 + lr;
    *(short4v*)&hidh[col * LDH + lg * 4] = *(short4v*)hv;
    *(short4v*)&hidl[col * LDH + lg * 4] = *(short4v*)lv;
  }

  // A2 fragments from LDS (col-major): a2[kt] elem j = hid[row=lr][k=kt*32+lg*8+j]
  short8 a2h[4], a2l[4];
#pragma unroll
  for (int kt = 0; kt < 4; ++kt) {
#pragma unroll
    for (int j = 0; j < 8; ++j) {
      int k = kt * 32 + lg * 8 + j;
      ((short*)&a2h[kt])[j] = hidh[k * LDH + lr];
      ((short*)&a2l[kt])[j] = hidl[k * LDH + lr];
    }
  }

  // GEMM2: acc = hid @ H2
#pragma unroll
  for (int ct = 0; ct < 8; ++ct) acc[ct] = (f32x4){0.f, 0.f, 0.f, 0.f};
#pragma unroll
  for (int kt = 0; kt < 4; ++kt) {
#pragma unroll
    for (int ct = 0; ct < 8; ++ct) {
      short8 bh = *(const short8*)&Hpk[((((size_t)2 * 4 + kt) * 8 + ct) * 64 + l) * 8];
      short8 bl = *(const short8*)&Hpk[((((size_t)3 * 4 + kt) * 8 + ct) * 64 + l) * 8];
      acc[ct] = __builtin_amdgcn_mfma_f32_16x16x32_bf16(a2l[kt], bh, acc[ct], 0, 0, 0);
      acc[ct] = __builtin_amdgcn_mfma_f32_16x16x32_bf16(a2h[kt], bl, acc[ct], 0, 0, 0);
      acc[ct] = __builtin_amdgcn_mfma_f32_16x16x32_bf16(a2h[kt], bh, acc[ct], 0, 0, 0);
    }
  }

  // epilogue: bf16 pack via LDS (reuse hidh) for coalesced row stores
#pragma unroll
  for (int ct = 0; ct < 8; ++ct) {
    short pk[4];
#pragma unroll
    for (int r = 0; r < 4; ++r) pk[r] = f2bf(acc[ct][r]);
    *(short4v*)&hidh[(ct * 16 + lr) * LDH + lg * 4] = *(short4v*)pk;
  }
#pragma unroll
  for (int s = 0; s < 4; ++s) {
    int row = s * 4 + lg;
    int grow = grow0 + row;
    if (grow < N) {
      short8 o;
#pragma unroll
      for (int j = 0; j < 8; ++j) o[j] = hidh[(lr * 8 + j) * LDH + row];
      *(short8*)&out2b[(size_t)grow * F + lr * 8] = o;
    }
  }
}

// ---------------- CSR rowptr from sorted adj_row ----------------
__global__ __launch_bounds__(256) void build_rowptr(
    const int* __restrict__ adj_row, int* __restrict__ rowptr, int E, int N) {
  int e = blockIdx.x * 256 + threadIdx.x;
  if (e >= E) return;
  int r = adj_row[e];
  int rprev = (e == 0) ? -1 : adj_row[e - 1];
  for (int q = rprev + 1; q <= r; ++q) rowptr[q] = e;
  if (e == E - 1) {
    for (int q = r + 1; q <= N; ++q) rowptr[q] = E;
  }
}

// ---------------- segment-sum SpMM: wave per row, bf16 gather ----------------
__global__ __launch_bounds__(256) void agg_rows2(
    const uint32_t* __restrict__ out2u,  // N x 64 uints (bf16 pairs)
    const int* __restrict__ rowptr, const int* __restrict__ adj_col,
    const float* __restrict__ adj_val, float* __restrict__ agg, int N) {
  int gw = (blockIdx.x * 256 + threadIdx.x) >> 6;
  const int lane = threadIdx.x & 63;
  if (gw >= N) return;
  const int row = __builtin_amdgcn_readfirstlane(gw);  // wave-uniform -> SGPR
  int e = rowptr[row];
  const int end = rowptr[row + 1];
  float accx = 0.f, accy = 0.f;

  for (; e + 8 <= end; e += 8) {
    int c[8]; float v[8]; uint32_t u[8];
#pragma unroll
    for (int j = 0; j < 8; ++j) { c[j] = adj_col[e + j]; v[j] = adj_val[e + j]; }
#pragma unroll
    for (int j = 0; j < 8; ++j) u[j] = out2u[(size_t)c[j] * 64 + lane];
#pragma unroll
    for (int j = 0; j < 8; ++j) {
      accx = fmaf(v[j], __uint_as_float(u[j] << 16), accx);
      accy = fmaf(v[j], __uint_as_float(u[j] & 0xFFFF0000u), accy);
    }
  }
  for (; e + 2 <= end; e += 2) {
    int c0 = adj_col[e], c1 = adj_col[e + 1];
    float v0 = adj_val[e], v1 = adj_val[e + 1];
    uint32_t u0 = out2u[(size_t)c0 * 64 + lane];
    uint32_t u1 = out2u[(size_t)c1 * 64 + lane];
    accx = fmaf(v0, __uint_as_float(u0 << 16), accx);
    accy = fmaf(v0, __uint_as_float(u0 & 0xFFFF0000u), accy);
    accx = fmaf(v1, __uint_as_float(u1 << 16), accx);
    accy = fmaf(v1, __uint_as_float(u1 & 0xFFFF0000u), accy);
  }
  if (e < end) {
    int c0 = adj_col[e];
    float v0 = adj_val[e];
    uint32_t u0 = out2u[(size_t)c0 * 64 + lane];
    accx = fmaf(v0, __uint_as_float(u0 << 16), accx);
    accy = fmaf(v0, __uint_as_float(u0 & 0xFFFF0000u), accy);
  }
  *(float2*)&agg[(size_t)row * F + lane * 2] = make_float2(accx, accy);
}

// ---------------- BN stats: per-feature sum & sumsq ----------------
__global__ __launch_bounds__(256) void reduce_stats(
    const float* __restrict__ agg, float* __restrict__ sumbuf, int N) {
  const int t = threadIdx.x;
  const int f4 = t & 31;   // float4 column
  const int rl = t >> 5;   // 0..7
  const int rpb = (N + gridDim.x - 1) / gridDim.x;
  const int r0 = blockIdx.x * rpb;
  const int r1 = min(N, r0 + rpb);
  float s0 = 0, s1 = 0, s2 = 0, s3 = 0, q0 = 0, q1 = 0, q2 = 0, q3 = 0;
  for (int r = r0 + rl; r < r1; r += 8) {
    float4 v = *(const float4*)&agg[(size_t)r * F + f4 * 4];
    s0 += v.x; s1 += v.y; s2 += v.z; s3 += v.w;
    q0 = fmaf(v.x, v.x, q0); q1 = fmaf(v.y, v.y, q1);
    q2 = fmaf(v.z, v.z, q2); q3 = fmaf(v.w, v.w, q3);
  }
  __shared__ float ls[256][4];
  __shared__ float lq[256][4];
  ls[t][0] = s0; ls[t][1] = s1; ls[t][2] = s2; ls[t][3] = s3;
  lq[t][0] = q0; lq[t][1] = q1; lq[t][2] = q2; lq[t][3] = q3;
  __syncthreads();
  if (t < 32) {
    float S[4] = {0, 0, 0, 0}, Q[4] = {0, 0, 0, 0};
#pragma unroll
    for (int g = 0; g < 8; ++g)
#pragma unroll
      for (int j = 0; j < 4; ++j) {
        S[j] += ls[t + 32 * g][j];
        Q[j] += lq[t + 32 * g][j];
      }
#pragma unroll
    for (int j = 0; j < 4; ++j) {
      atomicAdd(&sumbuf[t * 4 + j], S[j]);
      atomicAdd(&sumbuf[128 + t * 4 + j], Q[j]);
    }
  }
}

__global__ void finalize_stats(const float* __restrict__ sumbuf,
                               const float* __restrict__ gamma,
                               const float* __restrict__ beta,
                               float* __restrict__ ss, float invN) {
  int f = threadIdx.x;  // 128
  float mean = sumbuf[f] * invN;
  float var = sumbuf[128 + f] * invN - mean * mean;
  float inv = rsqrtf(var + 1e-5f);
  float sc = gamma[f] * inv;
  ss[f] = sc;
  ss[128 + f] = beta[f] - mean * sc;
}

__global__ __launch_bounds__(256) void bn_apply(
    float* __restrict__ out, const float* __restrict__ ss, int total4) {
  int idx = blockIdx.x * 256 + threadIdx.x;
  if (idx >= total4) return;
  int f4 = (idx & 31) * 4;
  float4 v = *(float4*)&out[(size_t)idx * 4];
  float4 sc = *(const float4*)&ss[f4];
  float4 sh = *(const float4*)&ss[128 + f4];
  v.x = fmaf(v.x, sc.x, sh.x);
  v.y = fmaf(v.y, sc.y, sh.y);
  v.z = fmaf(v.z, sc.z, sh.z);
  v.w = fmaf(v.w, sc.w, sh.w);
  *(float4*)&out[(size_t)idx * 4] = v;
}

// ---------------- launch ----------------
// ws layout (bytes):
//   [0,       131072)   Hpk bf16 fragments [2][2][4][8][64][8]
//   [131072,  132096)   sumbuf: sum[128], sumsq[128]  (memset each call)
//   [132096,  133120)   ss: scale[128], shift[128]
//   [133120,  337920)   rowptr (N+1 ints, padded)
//   [337920,  ...)      out2 bf16 [N*128]
extern "C" void kernel_launch(void* const* d_in, const int* in_sizes, int n_in,
                              void* d_out, int out_size, void* d_ws, size_t ws_size,
                              hipStream_t stream) {
  (void)n_in; (void)out_size; (void)ws_size;
  const float* input  = (const float*)d_in[0];
  const int*  adj_row = (const int*)d_in[1];
  const int*  adj_col = (const int*)d_in[2];
  const float* adj_val = (const float*)d_in[3];
  const float* w1 = (const float*)d_in[4];
  const float* w2 = (const float*)d_in[5];
  const float* gamma = (const float*)d_in[6];
  const float* beta  = (const float*)d_in[7];
  const int N = in_sizes[0] / F;
  const int E = in_sizes[1];

  char* ws = (char*)d_ws;
  short* Hpk = (short*)(ws);
  float* sumbuf = (float*)(ws + 131072);
  float* ss = (float*)(ws + 132096);
  int* rowptr = (int*)(ws + 133120);
  short* out2b = (short*)(ws + 337920);
  float* agg = (float*)d_out;

  (void)hipMemsetAsync(sumbuf, 0, 256 * sizeof(float), stream);
  build_hpk<<<16, 256, 0, stream>>>(w1, w2, Hpk);
  gemm_mfma<<<(N + 63) / 64, 256, 0, stream>>>(input, Hpk, out2b, N);
  build_rowptr<<<(E + 255) / 256, 256, 0, stream>>>(adj_row, rowptr, E, N);
  agg_rows2<<<(N * 64 + 255) / 256, 256, 0, stream>>>(
      (const uint32_t*)out2b, rowptr, adj_col, adj_val, agg, N);
  reduce_stats<<<512, 256, 0, stream>>>(agg, sumbuf, N);
  finalize_stats<<<1, 128, 0, stream>>>(sumbuf, gamma, beta, ss, 1.0f / (float)N);
  bn_apply<<<(N * 32 + 255) / 256, 256, 0, stream>>>(agg, ss, N * 32);
}

// Round 5
// 113.434 us; speedup vs baseline: 2.8447x; 1.2782x over previous
//
#include <hip/hip_runtime.h>
#include <cstddef>
#include <cstdint>

#define F 128
#define LDH 20  // padded col stride (shorts) for per-wave LDS; keeps 8B align
#define NB_STATS 512

typedef __attribute__((ext_vector_type(8))) short short8;
typedef __attribute__((ext_vector_type(4))) short short4v;
typedef __attribute__((ext_vector_type(4))) float f32x4;

__device__ __forceinline__ short f2bf(float f) {
  uint32_t u = __float_as_uint(f);
  uint32_t r = u + 0x7FFFu + ((u >> 16) & 1u);  // round-to-nearest-even
  return (short)(r >> 16);
}
__device__ __forceinline__ float bf2f(short h) {
  return __uint_as_float(((uint32_t)(uint16_t)h) << 16);
}

// ---------------- Hamilton build, packed in MFMA B-fragment order ----------------
// H[row][col] = sign * w[row&31][( (row>>5)^(col>>5) )*32 + (col&31)], neg mask 0x284E
// Hpk layout: [m(2)][part(2: hi,lo)][kt(4)][ct(8)][lane(64)][j(8)]
// B-frag: lane l, elem j  <->  B[kt*32 + (l>>4)*8 + j][ct*16 + (l&15)]
__global__ __launch_bounds__(256) void build_hpk(
    const float* __restrict__ w1, const float* __restrict__ w2,
    short* __restrict__ Hpk) {
  int idx = blockIdx.x * 256 + threadIdx.x;  // 4096: (m,kt,ct,lane)
  int m = idx >> 11;
  int kt = (idx >> 9) & 3;
  int ct = (idx >> 6) & 7;
  int l = idx & 63;
  int col = ct * 16 + (l & 15);
  const float* w = m ? w2 : w1;
  short hi[8], lo[8];
#pragma unroll
  for (int j = 0; j < 8; ++j) {
    int row = kt * 32 + (l >> 4) * 8 + j;  // k index of B
    int rb = row >> 5, cb = col >> 5;
    int neg = (0x284E >> (cb * 4 + rb)) & 1;
    float v = w[(row & 31) * 128 + (rb ^ cb) * 32 + (col & 31)];
    v = neg ? -v : v;
    short h = f2bf(v);
    hi[j] = h;
    lo[j] = f2bf(v - bf2f(h));
  }
  size_t b0 = ((((size_t)m * 2 + 0) * 4 + kt) * 8 + ct) * 64 + l;
  size_t b1 = ((((size_t)m * 2 + 1) * 4 + kt) * 8 + ct) * 64 + l;
  *(short8*)&Hpk[b0 * 8] = *(short8*)hi;
  *(short8*)&Hpk[b1 * 8] = *(short8*)lo;
}

// ---------------- fused MFMA GEMM: out2 = tanh(X @ H1) @ H2, bf16 out ----------------
// wave-per-16-rows, split-bf16 (hi/lo) operands, 3 mfma per tile, no barriers.
__global__ __launch_bounds__(256) void gemm_mfma(
    const float* __restrict__ input, const short* __restrict__ Hpk,
    short* __restrict__ out2b, int N) {
  __shared__ short lds[4][2][F * LDH];  // per-wave hi/lo hid tiles (40 KB)
  const int t = threadIdx.x;
  const int w = t >> 6, l = t & 63;
  const int lr = l & 15, lg = l >> 4;
  const int grow0 = blockIdx.x * 64 + w * 16;
  short* hidh = &lds[w][0][0];
  short* hidl = &lds[w][1][0];

  // A1 fragments from global f32, hi/lo split
  short8 a1h[4], a1l[4];
  {
    int arow = grow0 + lr;
    if (arow >= N) arow = N - 1;
    const float* xr = &input[(size_t)arow * F];
#pragma unroll
    for (int kt = 0; kt < 4; ++kt) {
      float xv[8];
      *(float4*)&xv[0] = *(const float4*)&xr[kt * 32 + lg * 8];
      *(float4*)&xv[4] = *(const float4*)&xr[kt * 32 + lg * 8 + 4];
#pragma unroll
      for (int j = 0; j < 8; ++j) {
        short h = f2bf(xv[j]);
        ((short*)&a1h[kt])[j] = h;
        ((short*)&a1l[kt])[j] = f2bf(xv[j] - bf2f(h));
      }
    }
  }

  // GEMM1: acc = X @ H1
  f32x4 acc[8];
#pragma unroll
  for (int ct = 0; ct < 8; ++ct) acc[ct] = (f32x4){0.f, 0.f, 0.f, 0.f};
#pragma unroll
  for (int kt = 0; kt < 4; ++kt) {
#pragma unroll
    for (int ct = 0; ct < 8; ++ct) {
      short8 bh = *(const short8*)&Hpk[((((size_t)0 * 4 + kt) * 8 + ct) * 64 + l) * 8];
      short8 bl = *(const short8*)&Hpk[((((size_t)1 * 4 + kt) * 8 + ct) * 64 + l) * 8];
      acc[ct] = __builtin_amdgcn_mfma_f32_16x16x32_bf16(a1l[kt], bh, acc[ct], 0, 0, 0);
      acc[ct] = __builtin_amdgcn_mfma_f32_16x16x32_bf16(a1h[kt], bl, acc[ct], 0, 0, 0);
      acc[ct] = __builtin_amdgcn_mfma_f32_16x16x32_bf16(a1h[kt], bh, acc[ct], 0, 0, 0);
    }
  }

  // hid = tanh(acc), split hi/lo, store col-major to per-wave LDS
  // C layout: col = ct*16 + lr, row = lg*4 + r
#pragma unroll
  for (int ct = 0; ct < 8; ++ct) {
    short hv[4], lv[4];
#pragma unroll
    for (int r = 0; r < 4; ++r) {
      float th = tanhf(acc[ct][r]);
      short h = f2bf(th);
      hv[r] = h;
      lv[r] = f2bf(th - bf2f(h));
    }
    int col = ct * 16 + lr;
    *(short4v*)&hidh[col * LDH + lg * 4] = *(short4v*)hv;
    *(short4v*)&hidl[col * LDH + lg * 4] = *(short4v*)lv;
  }

  // A2 fragments from LDS (col-major): a2[kt] elem j = hid[row=lr][k=kt*32+lg*8+j]
  short8 a2h[4], a2l[4];
#pragma unroll
  for (int kt = 0; kt < 4; ++kt) {
#pragma unroll
    for (int j = 0; j < 8; ++j) {
      int k = kt * 32 + lg * 8 + j;
      ((short*)&a2h[kt])[j] = hidh[k * LDH + lr];
      ((short*)&a2l[kt])[j] = hidl[k * LDH + lr];
    }
  }

  // GEMM2: acc = hid @ H2
#pragma unroll
  for (int ct = 0; ct < 8; ++ct) acc[ct] = (f32x4){0.f, 0.f, 0.f, 0.f};
#pragma unroll
  for (int kt = 0; kt < 4; ++kt) {
#pragma unroll
    for (int ct = 0; ct < 8; ++ct) {
      short8 bh = *(const short8*)&Hpk[((((size_t)2 * 4 + kt) * 8 + ct) * 64 + l) * 8];
      short8 bl = *(const short8*)&Hpk[((((size_t)3 * 4 + kt) * 8 + ct) * 64 + l) * 8];
      acc[ct] = __builtin_amdgcn_mfma_f32_16x16x32_bf16(a2l[kt], bh, acc[ct], 0, 0, 0);
      acc[ct] = __builtin_amdgcn_mfma_f32_16x16x32_bf16(a2h[kt], bl, acc[ct], 0, 0, 0);
      acc[ct] = __builtin_amdgcn_mfma_f32_16x16x32_bf16(a2h[kt], bh, acc[ct], 0, 0, 0);
    }
  }

  // epilogue: bf16 pack via LDS (reuse hidh) for coalesced row stores
#pragma unroll
  for (int ct = 0; ct < 8; ++ct) {
    short pk[4];
#pragma unroll
    for (int r = 0; r < 4; ++r) pk[r] = f2bf(acc[ct][r]);
    *(short4v*)&hidh[(ct * 16 + lr) * LDH + lg * 4] = *(short4v*)pk;
  }
#pragma unroll
  for (int s = 0; s < 4; ++s) {
    int row = s * 4 + lg;
    int grow = grow0 + row;
    if (grow < N) {
      short8 o;
#pragma unroll
      for (int j = 0; j < 8; ++j) o[j] = hidh[(lr * 8 + j) * LDH + row];
      *(short8*)&out2b[(size_t)grow * F + lr * 8] = o;
    }
  }
}

// ---------------- CSR rowptr from sorted adj_row ----------------
__global__ __launch_bounds__(256) void build_rowptr(
    const int* __restrict__ adj_row, int* __restrict__ rowptr, int E, int N) {
  int e = blockIdx.x * 256 + threadIdx.x;
  if (e >= E) return;
  int r = adj_row[e];
  int rprev = (e == 0) ? -1 : adj_row[e - 1];
  for (int q = rprev + 1; q <= r; ++q) rowptr[q] = e;
  if (e == E - 1) {
    for (int q = r + 1; q <= N; ++q) rowptr[q] = E;
  }
}

// ---------------- segment-sum SpMM: wave per row, bf16 gather ----------------
__global__ __launch_bounds__(256) void agg_rows2(
    const uint32_t* __restrict__ out2u,  // N x 64 uints (bf16 pairs)
    const int* __restrict__ rowptr, const int* __restrict__ adj_col,
    const float* __restrict__ adj_val, float* __restrict__ agg, int N) {
  int gw = (blockIdx.x * 256 + threadIdx.x) >> 6;
  const int lane = threadIdx.x & 63;
  if (gw >= N) return;
  const int row = __builtin_amdgcn_readfirstlane(gw);  // wave-uniform -> SGPR
  int e = rowptr[row];
  const int end = rowptr[row + 1];
  float accx = 0.f, accy = 0.f;

  for (; e + 8 <= end; e += 8) {
    int c[8]; float v[8]; uint32_t u[8];
#pragma unroll
    for (int j = 0; j < 8; ++j) { c[j] = adj_col[e + j]; v[j] = adj_val[e + j]; }
#pragma unroll
    for (int j = 0; j < 8; ++j) u[j] = out2u[(size_t)c[j] * 64 + lane];
#pragma unroll
    for (int j = 0; j < 8; ++j) {
      accx = fmaf(v[j], __uint_as_float(u[j] << 16), accx);
      accy = fmaf(v[j], __uint_as_float(u[j] & 0xFFFF0000u), accy);
    }
  }
  for (; e + 2 <= end; e += 2) {
    int c0 = adj_col[e], c1 = adj_col[e + 1];
    float v0 = adj_val[e], v1 = adj_val[e + 1];
    uint32_t u0 = out2u[(size_t)c0 * 64 + lane];
    uint32_t u1 = out2u[(size_t)c1 * 64 + lane];
    accx = fmaf(v0, __uint_as_float(u0 << 16), accx);
    accy = fmaf(v0, __uint_as_float(u0 & 0xFFFF0000u), accy);
    accx = fmaf(v1, __uint_as_float(u1 << 16), accx);
    accy = fmaf(v1, __uint_as_float(u1 & 0xFFFF0000u), accy);
  }
  if (e < end) {
    int c0 = adj_col[e];
    float v0 = adj_val[e];
    uint32_t u0 = out2u[(size_t)c0 * 64 + lane];
    accx = fmaf(v0, __uint_as_float(u0 << 16), accx);
    accy = fmaf(v0, __uint_as_float(u0 & 0xFFFF0000u), accy);
  }
  *(float2*)&agg[(size_t)row * F + lane * 2] = make_float2(accx, accy);
}

// ---------------- BN stats stage 1: per-block partial sum & sumsq (no atomics) ----------------
__global__ __launch_bounds__(256) void reduce_stats(
    const float* __restrict__ agg, float* __restrict__ partials, int N) {
  const int t = threadIdx.x;
  const int f4 = t & 31;   // float4 column
  const int rl = t >> 5;   // 0..7
  const int rpb = (N + gridDim.x - 1) / gridDim.x;
  const int r0 = blockIdx.x * rpb;
  const int r1 = min(N, r0 + rpb);
  float s0 = 0, s1 = 0, s2 = 0, s3 = 0, q0 = 0, q1 = 0, q2 = 0, q3 = 0;
  for (int r = r0 + rl; r < r1; r += 8) {
    float4 v = *(const float4*)&agg[(size_t)r * F + f4 * 4];
    s0 += v.x; s1 += v.y; s2 += v.z; s3 += v.w;
    q0 = fmaf(v.x, v.x, q0); q1 = fmaf(v.y, v.y, q1);
    q2 = fmaf(v.z, v.z, q2); q3 = fmaf(v.w, v.w, q3);
  }
  __shared__ float ls[256][4];
  __shared__ float lq[256][4];
  ls[t][0] = s0; ls[t][1] = s1; ls[t][2] = s2; ls[t][3] = s3;
  lq[t][0] = q0; lq[t][1] = q1; lq[t][2] = q2; lq[t][3] = q3;
  __syncthreads();
  if (t < 32) {
    float S[4] = {0, 0, 0, 0}, Q[4] = {0, 0, 0, 0};
#pragma unroll
    for (int g = 0; g < 8; ++g)
#pragma unroll
      for (int j = 0; j < 4; ++j) {
        S[j] += ls[t + 32 * g][j];
        Q[j] += lq[t + 32 * g][j];
      }
    float* dst = &partials[(size_t)blockIdx.x * 256];
#pragma unroll
    for (int j = 0; j < 4; ++j) {
      dst[t * 4 + j] = S[j];
      dst[128 + t * 4 + j] = Q[j];
    }
  }
}

// ---------------- BN stats stage 2: reduce partials, produce scale/shift ----------------
__global__ __launch_bounds__(256) void finalize_stats2(
    const float* __restrict__ partials, const float* __restrict__ gamma,
    const float* __restrict__ beta, float* __restrict__ ss, float invN, int nb) {
  const int t = threadIdx.x;  // 256
  float s = 0.f;
#pragma unroll 8
  for (int b = 0; b < nb; ++b) s += partials[(size_t)b * 256 + t];
  __shared__ float tot[256];
  tot[t] = s;
  __syncthreads();
  if (t < 128) {
    float mean = tot[t] * invN;
    float var = tot[128 + t] * invN - mean * mean;
    float inv = rsqrtf(var + 1e-5f);
    float sc = gamma[t] * inv;
    ss[t] = sc;
    ss[128 + t] = beta[t] - mean * sc;
  }
}

__global__ __launch_bounds__(256) void bn_apply(
    float* __restrict__ out, const float* __restrict__ ss, int total4) {
  int idx = blockIdx.x * 256 + threadIdx.x;
  if (idx >= total4) return;
  int f4 = (idx & 31) * 4;
  float4 v = *(float4*)&out[(size_t)idx * 4];
  float4 sc = *(const float4*)&ss[f4];
  float4 sh = *(const float4*)&ss[128 + f4];
  v.x = fmaf(v.x, sc.x, sh.x);
  v.y = fmaf(v.y, sc.y, sh.y);
  v.z = fmaf(v.z, sc.z, sh.z);
  v.w = fmaf(v.w, sc.w, sh.w);
  *(float4*)&out[(size_t)idx * 4] = v;
}

// ---------------- launch ----------------
// ws layout (bytes):
//   [0,       65536)    Hpk bf16 fragments [2][2][4][8][64][8]
//   [65536,   66560)    ss: scale[128], shift[128]
//   [66560,   590848)   partials: NB_STATS x 256 floats
//   [590848,  791552)   rowptr (N+1 ints, padded)
//   [791552,  ...)      out2 bf16 [N*128]
extern "C" void kernel_launch(void* const* d_in, const int* in_sizes, int n_in,
                              void* d_out, int out_size, void* d_ws, size_t ws_size,
                              hipStream_t stream) {
  (void)n_in; (void)out_size; (void)ws_size;
  const float* input  = (const float*)d_in[0];
  const int*  adj_row = (const int*)d_in[1];
  const int*  adj_col = (const int*)d_in[2];
  const float* adj_val = (const float*)d_in[3];
  const float* w1 = (const float*)d_in[4];
  const float* w2 = (const float*)d_in[5];
  const float* gamma = (const float*)d_in[6];
  const float* beta  = (const float*)d_in[7];
  const int N = in_sizes[0] / F;
  const int E = in_sizes[1];

  char* ws = (char*)d_ws;
  short* Hpk = (short*)(ws);
  float* ss = (float*)(ws + 65536);
  float* partials = (float*)(ws + 66560);
  int* rowptr = (int*)(ws + 590848);
  short* out2b = (short*)(ws + 791552);
  float* agg = (float*)d_out;

  build_hpk<<<16, 256, 0, stream>>>(w1, w2, Hpk);
  gemm_mfma<<<(N + 63) / 64, 256, 0, stream>>>(input, Hpk, out2b, N);
  build_rowptr<<<(E + 255) / 256, 256, 0, stream>>>(adj_row, rowptr, E, N);
  agg_rows2<<<(N * 64 + 255) / 256, 256, 0, stream>>>(
      (const uint32_t*)out2b, rowptr, adj_col, adj_val, agg, N);
  reduce_stats<<<NB_STATS, 256, 0, stream>>>(agg, partials, N);
  finalize_stats2<<<1, 256, 0, stream>>>(partials, gamma, beta, ss, 1.0f / (float)N, NB_STATS);
  bn_apply<<<(N * 32 + 255) / 256, 256, 0, stream>>>(agg, ss, N * 32);
}

// Round 6
// 108.904 us; speedup vs baseline: 2.9630x; 1.0416x over previous
//
#include <hip/hip_runtime.h>
#include <cstddef>
#include <cstdint>

#define F 128
#define LDK 136  // hid LDS row stride in shorts (272B, 16B aligned)
#define NB_STATS 512

typedef __attribute__((ext_vector_type(8))) short short8;
typedef __attribute__((ext_vector_type(4))) float f32x4;

__device__ __forceinline__ short f2bf(float f) {
  uint32_t u = __float_as_uint(f);
  uint32_t r = u + 0x7FFFu + ((u >> 16) & 1u);  // round-to-nearest-even
  return (short)(r >> 16);
}
__device__ __forceinline__ float bf2f(short h) {
  return __uint_as_float(((uint32_t)(uint16_t)h) << 16);
}

// ---------------- Hamilton build, packed in MFMA B-fragment order ----------------
// H[row][col] = sign * w[row&31][( (row>>5)^(col>>5) )*32 + (col&31)], neg mask 0x284E
// Hpk layout: [m(2)][part(2: hi,lo)][kt(4)][ct(8)][lane(64)][j(8)]
// B-frag: lane l, elem j  <->  B[kt*32 + (l>>4)*8 + j][ct*16 + (l&15)]
__global__ __launch_bounds__(256) void build_hpk(
    const float* __restrict__ w1, const float* __restrict__ w2,
    short* __restrict__ Hpk) {
  int idx = blockIdx.x * 256 + threadIdx.x;  // 4096: (m,kt,ct,lane)
  int m = idx >> 11;
  int kt = (idx >> 9) & 3;
  int ct = (idx >> 6) & 7;
  int l = idx & 63;
  int col = ct * 16 + (l & 15);
  const float* w = m ? w2 : w1;
  short hi[8], lo[8];
#pragma unroll
  for (int j = 0; j < 8; ++j) {
    int row = kt * 32 + (l >> 4) * 8 + j;  // k index of B
    int rb = row >> 5, cb = col >> 5;
    int neg = (0x284E >> (cb * 4 + rb)) & 1;
    float v = w[(row & 31) * 128 + (rb ^ cb) * 32 + (col & 31)];
    v = neg ? -v : v;
    short h = f2bf(v);
    hi[j] = h;
    lo[j] = f2bf(v - bf2f(h));
  }
  size_t b0 = ((((size_t)m * 2 + 0) * 4 + kt) * 8 + ct) * 64 + l;
  size_t b1 = ((((size_t)m * 2 + 1) * 4 + kt) * 8 + ct) * 64 + l;
  *(short8*)&Hpk[b0 * 8] = *(short8*)hi;
  *(short8*)&Hpk[b1 * 8] = *(short8*)lo;
}

// ---------------- fused MFMA GEMM: out2 = tanh(X @ H1) @ H2, bf16 out ----------------
// 32 rows/wave (2x16 subtiles share B-frags), A-hi only, B hi+lo (2 mfma/tile).
// hid kept in per-wave LDS row-major; no barriers.
__global__ __launch_bounds__(256) void gemm_mfma(
    const float* __restrict__ input, const short* __restrict__ Hpk,
    short* __restrict__ out2b, int N) {
  __shared__ short lds[4][32 * LDK];  // per-wave hid/epilogue tile (34.8 KB)
  const int t = threadIdx.x;
  const int w = t >> 6, l = t & 63;
  const int lr = l & 15, lg = l >> 4;
  const int grow0 = blockIdx.x * 128 + w * 32;
  short* hid = &lds[w][0];

  // A1 fragments (hi only) from global f32
  short8 a1h[2][4];
#pragma unroll
  for (int T = 0; T < 2; ++T) {
    int arow = grow0 + T * 16 + lr;
    if (arow >= N) arow = N - 1;
    const float* xr = &input[(size_t)arow * F];
#pragma unroll
    for (int kt = 0; kt < 4; ++kt) {
      float xv[8];
      *(float4*)&xv[0] = *(const float4*)&xr[kt * 32 + lg * 8];
      *(float4*)&xv[4] = *(const float4*)&xr[kt * 32 + lg * 8 + 4];
#pragma unroll
      for (int j = 0; j < 8; ++j) ((short*)&a1h[T][kt])[j] = f2bf(xv[j]);
    }
  }

  // GEMM1: acc = X @ H1
  f32x4 acc[2][8];
#pragma unroll
  for (int T = 0; T < 2; ++T)
#pragma unroll
    for (int ct = 0; ct < 8; ++ct) acc[T][ct] = (f32x4){0.f, 0.f, 0.f, 0.f};
#pragma unroll
  for (int kt = 0; kt < 4; ++kt) {
#pragma unroll
    for (int ct = 0; ct < 8; ++ct) {
      short8 bh = *(const short8*)&Hpk[((((size_t)0 * 4 + kt) * 8 + ct) * 64 + l) * 8];
      short8 bl = *(const short8*)&Hpk[((((size_t)1 * 4 + kt) * 8 + ct) * 64 + l) * 8];
      acc[0][ct] = __builtin_amdgcn_mfma_f32_16x16x32_bf16(a1h[0][kt], bl, acc[0][ct], 0, 0, 0);
      acc[0][ct] = __builtin_amdgcn_mfma_f32_16x16x32_bf16(a1h[0][kt], bh, acc[0][ct], 0, 0, 0);
      acc[1][ct] = __builtin_amdgcn_mfma_f32_16x16x32_bf16(a1h[1][kt], bl, acc[1][ct], 0, 0, 0);
      acc[1][ct] = __builtin_amdgcn_mfma_f32_16x16x32_bf16(a1h[1][kt], bh, acc[1][ct], 0, 0, 0);
    }
  }

  // hid = tanh(acc) -> LDS row-major (C layout: row=lg*4+r, col=ct*16+lr)
#pragma unroll
  for (int T = 0; T < 2; ++T)
#pragma unroll
    for (int ct = 0; ct < 8; ++ct)
#pragma unroll
      for (int r = 0; r < 4; ++r)
        hid[(T * 16 + lg * 4 + r) * LDK + ct * 16 + lr] = f2bf(tanhf(acc[T][ct][r]));

  // A2 fragments: vectorized b128 reads (row=lr, k contiguous)
  short8 a2h[2][4];
#pragma unroll
  for (int T = 0; T < 2; ++T)
#pragma unroll
    for (int kt = 0; kt < 4; ++kt)
      a2h[T][kt] = *(short8*)&hid[(T * 16 + lr) * LDK + kt * 32 + lg * 8];

  // GEMM2: acc = hid @ H2
#pragma unroll
  for (int T = 0; T < 2; ++T)
#pragma unroll
    for (int ct = 0; ct < 8; ++ct) acc[T][ct] = (f32x4){0.f, 0.f, 0.f, 0.f};
#pragma unroll
  for (int kt = 0; kt < 4; ++kt) {
#pragma unroll
    for (int ct = 0; ct < 8; ++ct) {
      short8 bh = *(const short8*)&Hpk[((((size_t)2 * 4 + kt) * 8 + ct) * 64 + l) * 8];
      short8 bl = *(const short8*)&Hpk[((((size_t)3 * 4 + kt) * 8 + ct) * 64 + l) * 8];
      acc[0][ct] = __builtin_amdgcn_mfma_f32_16x16x32_bf16(a2h[0][kt], bl, acc[0][ct], 0, 0, 0);
      acc[0][ct] = __builtin_amdgcn_mfma_f32_16x16x32_bf16(a2h[0][kt], bh, acc[0][ct], 0, 0, 0);
      acc[1][ct] = __builtin_amdgcn_mfma_f32_16x16x32_bf16(a2h[1][kt], bl, acc[1][ct], 0, 0, 0);
      acc[1][ct] = __builtin_amdgcn_mfma_f32_16x16x32_bf16(a2h[1][kt], bh, acc[1][ct], 0, 0, 0);
    }
  }

  // epilogue: bf16 pack -> LDS (reuse hid), then coalesced row stores
#pragma unroll
  for (int T = 0; T < 2; ++T)
#pragma unroll
    for (int ct = 0; ct < 8; ++ct)
#pragma unroll
      for (int r = 0; r < 4; ++r)
        hid[(T * 16 + lg * 4 + r) * LDK + ct * 16 + lr] = f2bf(acc[T][ct][r]);
#pragma unroll
  for (int i = 0; i < 8; ++i) {
    int chunk = i * 64 + l;
    int row = chunk >> 4, pos = chunk & 15;
    int grow = grow0 + row;
    if (grow < N)
      *(short8*)&out2b[(size_t)grow * F + pos * 8] = *(short8*)&hid[row * LDK + pos * 8];
  }
}

// ---------------- CSR rowptr from sorted adj_row ----------------
__global__ __launch_bounds__(256) void build_rowptr(
    const int* __restrict__ adj_row, int* __restrict__ rowptr, int E, int N) {
  int e = blockIdx.x * 256 + threadIdx.x;
  if (e >= E) return;
  int r = adj_row[e];
  int rprev = (e == 0) ? -1 : adj_row[e - 1];
  for (int q = rprev + 1; q <= r; ++q) rowptr[q] = e;
  if (e == E - 1) {
    for (int q = r + 1; q <= N; ++q) rowptr[q] = E;
  }
}

// ---------------- segment-sum SpMM: wave per row, bf16 gather, 16-deep ILP ----------------
__global__ __launch_bounds__(256) void agg_rows2(
    const uint32_t* __restrict__ out2u,  // N x 64 uints (bf16 pairs)
    const int* __restrict__ rowptr, const int* __restrict__ adj_col,
    const float* __restrict__ adj_val, float* __restrict__ agg, int N) {
  int gw = (blockIdx.x * 256 + threadIdx.x) >> 6;
  const int lane = threadIdx.x & 63;
  if (gw >= N) return;
  const int row = __builtin_amdgcn_readfirstlane(gw);  // wave-uniform -> SGPR
  int e = rowptr[row];
  const int end = rowptr[row + 1];
  float accx = 0.f, accy = 0.f;

  for (; e + 16 <= end; e += 16) {
    int c[16]; float v[16]; uint32_t u[16];
#pragma unroll
    for (int j = 0; j < 16; ++j) { c[j] = adj_col[e + j]; v[j] = adj_val[e + j]; }
#pragma unroll
    for (int j = 0; j < 16; ++j) u[j] = out2u[(size_t)c[j] * 64 + lane];
#pragma unroll
    for (int j = 0; j < 16; ++j) {
      accx = fmaf(v[j], __uint_as_float(u[j] << 16), accx);
      accy = fmaf(v[j], __uint_as_float(u[j] & 0xFFFF0000u), accy);
    }
  }
  for (; e + 4 <= end; e += 4) {
    int c[4]; float v[4]; uint32_t u[4];
#pragma unroll
    for (int j = 0; j < 4; ++j) { c[j] = adj_col[e + j]; v[j] = adj_val[e + j]; }
#pragma unroll
    for (int j = 0; j < 4; ++j) u[j] = out2u[(size_t)c[j] * 64 + lane];
#pragma unroll
    for (int j = 0; j < 4; ++j) {
      accx = fmaf(v[j], __uint_as_float(u[j] << 16), accx);
      accy = fmaf(v[j], __uint_as_float(u[j] & 0xFFFF0000u), accy);
    }
  }
  for (; e < end; ++e) {
    int c0 = adj_col[e];
    float v0 = adj_val[e];
    uint32_t u0 = out2u[(size_t)c0 * 64 + lane];
    accx = fmaf(v0, __uint_as_float(u0 << 16), accx);
    accy = fmaf(v0, __uint_as_float(u0 & 0xFFFF0000u), accy);
  }
  *(float2*)&agg[(size_t)row * F + lane * 2] = make_float2(accx, accy);
}

// ---------------- BN stats stage 1: per-block partial sum & sumsq (no atomics) ----------------
__global__ __launch_bounds__(256) void reduce_stats(
    const float* __restrict__ agg, float* __restrict__ partials, int N) {
  const int t = threadIdx.x;
  const int f4 = t & 31;   // float4 column
  const int rl = t >> 5;   // 0..7
  const int rpb = (N + gridDim.x - 1) / gridDim.x;
  const int r0 = blockIdx.x * rpb;
  const int r1 = min(N, r0 + rpb);
  float s0 = 0, s1 = 0, s2 = 0, s3 = 0, q0 = 0, q1 = 0, q2 = 0, q3 = 0;
  for (int r = r0 + rl; r < r1; r += 8) {
    float4 v = *(const float4*)&agg[(size_t)r * F + f4 * 4];
    s0 += v.x; s1 += v.y; s2 += v.z; s3 += v.w;
    q0 = fmaf(v.x, v.x, q0); q1 = fmaf(v.y, v.y, q1);
    q2 = fmaf(v.z, v.z, q2); q3 = fmaf(v.w, v.w, q3);
  }
  __shared__ float ls[256][4];
  __shared__ float lq[256][4];
  ls[t][0] = s0; ls[t][1] = s1; ls[t][2] = s2; ls[t][3] = s3;
  lq[t][0] = q0; lq[t][1] = q1; lq[t][2] = q2; lq[t][3] = q3;
  __syncthreads();
  if (t < 32) {
    float S[4] = {0, 0, 0, 0}, Q[4] = {0, 0, 0, 0};
#pragma unroll
    for (int g = 0; g < 8; ++g)
#pragma unroll
      for (int j = 0; j < 4; ++j) {
        S[j] += ls[t + 32 * g][j];
        Q[j] += lq[t + 32 * g][j];
      }
    float* dst = &partials[(size_t)blockIdx.x * 256];
#pragma unroll
    for (int j = 0; j < 4; ++j) {
      dst[t * 4 + j] = S[j];
      dst[128 + t * 4 + j] = Q[j];
    }
  }
}

// ---------------- BN stats stage 2: reduce partials, produce scale/shift ----------------
__global__ __launch_bounds__(256) void finalize_stats2(
    const float* __restrict__ partials, const float* __restrict__ gamma,
    const float* __restrict__ beta, float* __restrict__ ss, float invN, int nb) {
  const int t = threadIdx.x;  // 256
  float s = 0.f;
#pragma unroll 8
  for (int b = 0; b < nb; ++b) s += partials[(size_t)b * 256 + t];
  __shared__ float tot[256];
  tot[t] = s;
  __syncthreads();
  if (t < 128) {
    float mean = tot[t] * invN;
    float var = tot[128 + t] * invN - mean * mean;
    float inv = rsqrtf(var + 1e-5f);
    float sc = gamma[t] * inv;
    ss[t] = sc;
    ss[128 + t] = beta[t] - mean * sc;
  }
}

__global__ __launch_bounds__(256) void bn_apply(
    float* __restrict__ out, const float* __restrict__ ss, int total4) {
  int idx = blockIdx.x * 256 + threadIdx.x;
  if (idx >= total4) return;
  int f4 = (idx & 31) * 4;
  float4 v = *(float4*)&out[(size_t)idx * 4];
  float4 sc = *(const float4*)&ss[f4];
  float4 sh = *(const float4*)&ss[128 + f4];
  v.x = fmaf(v.x, sc.x, sh.x);
  v.y = fmaf(v.y, sc.y, sh.y);
  v.z = fmaf(v.z, sc.z, sh.z);
  v.w = fmaf(v.w, sc.w, sh.w);
  *(float4*)&out[(size_t)idx * 4] = v;
}

// ---------------- launch ----------------
// ws layout (bytes):
//   [0,       65536)    Hpk bf16 fragments [2][2][4][8][64][8]
//   [65536,   66560)    ss: scale[128], shift[128]
//   [66560,   590848)   partials: NB_STATS x 256 floats
//   [590848,  791552)   rowptr (N+1 ints, padded)
//   [791552,  ...)      out2 bf16 [N*128]
extern "C" void kernel_launch(void* const* d_in, const int* in_sizes, int n_in,
                              void* d_out, int out_size, void* d_ws, size_t ws_size,
                              hipStream_t stream) {
  (void)n_in; (void)out_size; (void)ws_size;
  const float* input  = (const float*)d_in[0];
  const int*  adj_row = (const int*)d_in[1];
  const int*  adj_col = (const int*)d_in[2];
  const float* adj_val = (const float*)d_in[3];
  const float* w1 = (const float*)d_in[4];
  const float* w2 = (const float*)d_in[5];
  const float* gamma = (const float*)d_in[6];
  const float* beta  = (const float*)d_in[7];
  const int N = in_sizes[0] / F;
  const int E = in_sizes[1];

  char* ws = (char*)d_ws;
  short* Hpk = (short*)(ws);
  float* ss = (float*)(ws + 65536);
  float* partials = (float*)(ws + 66560);
  int* rowptr = (int*)(ws + 590848);
  short* out2b = (short*)(ws + 791552);
  float* agg = (float*)d_out;

  build_hpk<<<16, 256, 0, stream>>>(w1, w2, Hpk);
  gemm_mfma<<<(N + 127) / 128, 256, 0, stream>>>(input, Hpk, out2b, N);
  build_rowptr<<<(E + 255) / 256, 256, 0, stream>>>(adj_row, rowptr, E, N);
  agg_rows2<<<(N * 64 + 255) / 256, 256, 0, stream>>>(
      (const uint32_t*)out2b, rowptr, adj_col, adj_val, agg, N);
  reduce_stats<<<NB_STATS, 256, 0, stream>>>(agg, partials, N);
  finalize_stats2<<<1, 256, 0, stream>>>(partials, gamma, beta, ss, 1.0f / (float)N, NB_STATS);
  bn_apply<<<(N * 32 + 255) / 256, 256, 0, stream>>>(agg, ss, N * 32);
}

// Round 7
// 107.630 us; speedup vs baseline: 2.9981x; 1.0118x over previous
//
#include <hip/hip_runtime.h>
#include <cstddef>
#include <cstdint>

#define F 128
#define LDK 136  // hid LDS row stride in shorts (272B, 16B aligned)
#define NB_STATS 512

typedef __attribute__((ext_vector_type(8))) short short8;
typedef __attribute__((ext_vector_type(4))) float f32x4;

__device__ __forceinline__ short f2bf(float f) {
  uint32_t u = __float_as_uint(f);
  uint32_t r = u + 0x7FFFu + ((u >> 16) & 1u);  // round-to-nearest-even
  return (short)(r >> 16);
}
__device__ __forceinline__ float bf2f(short h) {
  return __uint_as_float(((uint32_t)(uint16_t)h) << 16);
}

// ---------------- setup: Hamilton pack (blocks 0..15) + CSR rowptr (rest) ----------------
// H[row][col] = sign * w[row&31][( (row>>5)^(col>>5) )*32 + (col&31)], neg mask 0x284E
// Hpk layout: [m(2)][part(2: hi,lo)][kt(4)][ct(8)][lane(64)][j(8)]
// B-frag: lane l, elem j  <->  B[kt*32 + (l>>4)*8 + j][ct*16 + (l&15)]
__global__ __launch_bounds__(256) void setup_kernel(
    const float* __restrict__ w1, const float* __restrict__ w2,
    short* __restrict__ Hpk, const int* __restrict__ adj_row,
    int* __restrict__ rowptr, int E, int N) {
  if (blockIdx.x < 16) {
    int idx = blockIdx.x * 256 + threadIdx.x;  // 4096: (m,kt,ct,lane)
    int m = idx >> 11;
    int kt = (idx >> 9) & 3;
    int ct = (idx >> 6) & 7;
    int l = idx & 63;
    int col = ct * 16 + (l & 15);
    const float* w = m ? w2 : w1;
    short hi[8], lo[8];
#pragma unroll
    for (int j = 0; j < 8; ++j) {
      int row = kt * 32 + (l >> 4) * 8 + j;  // k index of B
      int rb = row >> 5, cb = col >> 5;
      int neg = (0x284E >> (cb * 4 + rb)) & 1;
      float v = w[(row & 31) * 128 + (rb ^ cb) * 32 + (col & 31)];
      v = neg ? -v : v;
      short h = f2bf(v);
      hi[j] = h;
      lo[j] = f2bf(v - bf2f(h));
    }
    size_t b0 = ((((size_t)m * 2 + 0) * 4 + kt) * 8 + ct) * 64 + l;
    size_t b1 = ((((size_t)m * 2 + 1) * 4 + kt) * 8 + ct) * 64 + l;
    *(short8*)&Hpk[b0 * 8] = *(short8*)hi;
    *(short8*)&Hpk[b1 * 8] = *(short8*)lo;
  } else {
    int e = (blockIdx.x - 16) * 256 + threadIdx.x;
    if (e >= E) return;
    int r = adj_row[e];
    int rprev = (e == 0) ? -1 : adj_row[e - 1];
    for (int q = rprev + 1; q <= r; ++q) rowptr[q] = e;
    if (e == E - 1) {
      for (int q = r + 1; q <= N; ++q) rowptr[q] = E;
    }
  }
}

// ---------------- fused MFMA GEMM: out2 = tanh(X @ H1) @ H2, bf16 out ----------------
// 32 rows/wave (2x16 subtiles share B-frags), A-hi only, B hi+lo (2 mfma/tile).
// hid kept in per-wave LDS row-major; no barriers.
__global__ __launch_bounds__(256) void gemm_mfma(
    const float* __restrict__ input, const short* __restrict__ Hpk,
    short* __restrict__ out2b, int N) {
  __shared__ short lds[4][32 * LDK];  // per-wave hid/epilogue tile (34.8 KB)
  const int t = threadIdx.x;
  const int w = t >> 6, l = t & 63;
  const int lr = l & 15, lg = l >> 4;
  const int grow0 = blockIdx.x * 128 + w * 32;
  short* hid = &lds[w][0];

  // A1 fragments (hi only) from global f32
  short8 a1h[2][4];
#pragma unroll
  for (int T = 0; T < 2; ++T) {
    int arow = grow0 + T * 16 + lr;
    if (arow >= N) arow = N - 1;
    const float* xr = &input[(size_t)arow * F];
#pragma unroll
    for (int kt = 0; kt < 4; ++kt) {
      float xv[8];
      *(float4*)&xv[0] = *(const float4*)&xr[kt * 32 + lg * 8];
      *(float4*)&xv[4] = *(const float4*)&xr[kt * 32 + lg * 8 + 4];
#pragma unroll
      for (int j = 0; j < 8; ++j) ((short*)&a1h[T][kt])[j] = f2bf(xv[j]);
    }
  }

  // GEMM1: acc = X @ H1
  f32x4 acc[2][8];
#pragma unroll
  for (int T = 0; T < 2; ++T)
#pragma unroll
    for (int ct = 0; ct < 8; ++ct) acc[T][ct] = (f32x4){0.f, 0.f, 0.f, 0.f};
#pragma unroll
  for (int kt = 0; kt < 4; ++kt) {
#pragma unroll
    for (int ct = 0; ct < 8; ++ct) {
      short8 bh = *(const short8*)&Hpk[((((size_t)0 * 4 + kt) * 8 + ct) * 64 + l) * 8];
      short8 bl = *(const short8*)&Hpk[((((size_t)1 * 4 + kt) * 8 + ct) * 64 + l) * 8];
      acc[0][ct] = __builtin_amdgcn_mfma_f32_16x16x32_bf16(a1h[0][kt], bl, acc[0][ct], 0, 0, 0);
      acc[0][ct] = __builtin_amdgcn_mfma_f32_16x16x32_bf16(a1h[0][kt], bh, acc[0][ct], 0, 0, 0);
      acc[1][ct] = __builtin_amdgcn_mfma_f32_16x16x32_bf16(a1h[1][kt], bl, acc[1][ct], 0, 0, 0);
      acc[1][ct] = __builtin_amdgcn_mfma_f32_16x16x32_bf16(a1h[1][kt], bh, acc[1][ct], 0, 0, 0);
    }
  }

  // hid = tanh(acc) -> LDS row-major (C layout: row=lg*4+r, col=ct*16+lr)
#pragma unroll
  for (int T = 0; T < 2; ++T)
#pragma unroll
    for (int ct = 0; ct < 8; ++ct)
#pragma unroll
      for (int r = 0; r < 4; ++r)
        hid[(T * 16 + lg * 4 + r) * LDK + ct * 16 + lr] = f2bf(tanhf(acc[T][ct][r]));

  // A2 fragments: vectorized b128 reads (row=lr, k contiguous)
  short8 a2h[2][4];
#pragma unroll
  for (int T = 0; T < 2; ++T)
#pragma unroll
    for (int kt = 0; kt < 4; ++kt)
      a2h[T][kt] = *(short8*)&hid[(T * 16 + lr) * LDK + kt * 32 + lg * 8];

  // GEMM2: acc = hid @ H2
#pragma unroll
  for (int T = 0; T < 2; ++T)
#pragma unroll
    for (int ct = 0; ct < 8; ++ct) acc[T][ct] = (f32x4){0.f, 0.f, 0.f, 0.f};
#pragma unroll
  for (int kt = 0; kt < 4; ++kt) {
#pragma unroll
    for (int ct = 0; ct < 8; ++ct) {
      short8 bh = *(const short8*)&Hpk[((((size_t)2 * 4 + kt) * 8 + ct) * 64 + l) * 8];
      short8 bl = *(const short8*)&Hpk[((((size_t)3 * 4 + kt) * 8 + ct) * 64 + l) * 8];
      acc[0][ct] = __builtin_amdgcn_mfma_f32_16x16x32_bf16(a2h[0][kt], bl, acc[0][ct], 0, 0, 0);
      acc[0][ct] = __builtin_amdgcn_mfma_f32_16x16x32_bf16(a2h[0][kt], bh, acc[0][ct], 0, 0, 0);
      acc[1][ct] = __builtin_amdgcn_mfma_f32_16x16x32_bf16(a2h[1][kt], bl, acc[1][ct], 0, 0, 0);
      acc[1][ct] = __builtin_amdgcn_mfma_f32_16x16x32_bf16(a2h[1][kt], bh, acc[1][ct], 0, 0, 0);
    }
  }

  // epilogue: bf16 pack -> LDS (reuse hid), then coalesced row stores
#pragma unroll
  for (int T = 0; T < 2; ++T)
#pragma unroll
    for (int ct = 0; ct < 8; ++ct)
#pragma unroll
      for (int r = 0; r < 4; ++r)
        hid[(T * 16 + lg * 4 + r) * LDK + ct * 16 + lr] = f2bf(acc[T][ct][r]);
#pragma unroll
  for (int i = 0; i < 8; ++i) {
    int chunk = i * 64 + l;
    int row = chunk >> 4, pos = chunk & 15;
    int grow = grow0 + row;
    if (grow < N)
      *(short8*)&out2b[(size_t)grow * F + pos * 8] = *(short8*)&hid[row * LDK + pos * 8];
  }
}

// ---------------- segment-sum SpMM: wave/row, 16 lanes/edge dwordx4 gather ----------------
// One VMEM instruction covers 4 edges (16B/lane x 16 lanes = 256B row each).
__global__ __launch_bounds__(256) void agg_rows3(
    const uint32_t* __restrict__ out2u,  // N x 64 uints (bf16 pairs)
    const int* __restrict__ rowptr, const int* __restrict__ adj_col,
    const float* __restrict__ adj_val, float* __restrict__ agg, int N) {
  int gw = (blockIdx.x * 256 + threadIdx.x) >> 6;
  if (gw >= N) return;
  const int lane = threadIdx.x & 63;
  const int sub = lane >> 4;   // which edge within a quad
  const int fl = lane & 15;    // 16B feature chunk (8 bf16 feats)
  const int row = __builtin_amdgcn_readfirstlane(gw);
  const int start = rowptr[row];
  const int end = rowptr[row + 1];
  float acc[8];
#pragma unroll
  for (int j = 0; j < 8; ++j) acc[j] = 0.f;

  int e = start;
  // 4 quads (16 edges) in flight
  for (; e + 16 <= end; e += 16) {
    int c[4]; float v[4]; uint4 u[4];
#pragma unroll
    for (int q = 0; q < 4; ++q) {
      int ee = e + q * 4 + sub;
      c[q] = adj_col[ee];
      v[q] = adj_val[ee];
    }
#pragma unroll
    for (int q = 0; q < 4; ++q)
      u[q] = *(const uint4*)&out2u[(size_t)c[q] * 64 + fl * 4];
#pragma unroll
    for (int q = 0; q < 4; ++q) {
#pragma unroll
      for (int k = 0; k < 4; ++k) {
        uint32_t uu = ((const uint32_t*)&u[q])[k];
        acc[2 * k]     = fmaf(v[q], __uint_as_float(uu << 16), acc[2 * k]);
        acc[2 * k + 1] = fmaf(v[q], __uint_as_float(uu & 0xFFFF0000u), acc[2 * k + 1]);
      }
    }
  }
  // quad tail (clamped)
  for (; e < end; e += 4) {
    int ee = e + sub;
    bool valid = ee < end;
    int c0 = adj_col[valid ? ee : end - 1];
    float v0 = valid ? adj_val[ee] : 0.f;
    uint4 u = *(const uint4*)&out2u[(size_t)c0 * 64 + fl * 4];
#pragma unroll
    for (int k = 0; k < 4; ++k) {
      uint32_t uu = ((const uint32_t*)&u)[k];
      acc[2 * k]     = fmaf(v0, __uint_as_float(uu << 16), acc[2 * k]);
      acc[2 * k + 1] = fmaf(v0, __uint_as_float(uu & 0xFFFF0000u), acc[2 * k + 1]);
    }
  }
  // fold the 4 edge-subgroups (lanes +-16, +-32)
#pragma unroll
  for (int j = 0; j < 8; ++j) {
    acc[j] += __shfl_xor(acc[j], 16, 64);
    acc[j] += __shfl_xor(acc[j], 32, 64);
  }
  if (sub == 0) {
    float4 lo4 = make_float4(acc[0], acc[1], acc[2], acc[3]);
    float4 hi4 = make_float4(acc[4], acc[5], acc[6], acc[7]);
    *(float4*)&agg[(size_t)row * F + fl * 8] = lo4;
    *(float4*)&agg[(size_t)row * F + fl * 8 + 4] = hi4;
  }
}

// ---------------- BN stats stage 1: per-block partial sum & sumsq (no atomics) ----------------
__global__ __launch_bounds__(256) void reduce_stats(
    const float* __restrict__ agg, float* __restrict__ partials, int N) {
  const int t = threadIdx.x;
  const int f4 = t & 31;   // float4 column
  const int rl = t >> 5;   // 0..7
  const int rpb = (N + gridDim.x - 1) / gridDim.x;
  const int r0 = blockIdx.x * rpb;
  const int r1 = min(N, r0 + rpb);
  float s0 = 0, s1 = 0, s2 = 0, s3 = 0, q0 = 0, q1 = 0, q2 = 0, q3 = 0;
  for (int r = r0 + rl; r < r1; r += 8) {
    float4 v = *(const float4*)&agg[(size_t)r * F + f4 * 4];
    s0 += v.x; s1 += v.y; s2 += v.z; s3 += v.w;
    q0 = fmaf(v.x, v.x, q0); q1 = fmaf(v.y, v.y, q1);
    q2 = fmaf(v.z, v.z, q2); q3 = fmaf(v.w, v.w, q3);
  }
  __shared__ float ls[256][4];
  __shared__ float lq[256][4];
  ls[t][0] = s0; ls[t][1] = s1; ls[t][2] = s2; ls[t][3] = s3;
  lq[t][0] = q0; lq[t][1] = q1; lq[t][2] = q2; lq[t][3] = q3;
  __syncthreads();
  if (t < 32) {
    float S[4] = {0, 0, 0, 0}, Q[4] = {0, 0, 0, 0};
#pragma unroll
    for (int g = 0; g < 8; ++g)
#pragma unroll
      for (int j = 0; j < 4; ++j) {
        S[j] += ls[t + 32 * g][j];
        Q[j] += lq[t + 32 * g][j];
      }
    float* dst = &partials[(size_t)blockIdx.x * 256];
#pragma unroll
    for (int j = 0; j < 4; ++j) {
      dst[t * 4 + j] = S[j];
      dst[128 + t * 4 + j] = Q[j];
    }
  }
}

// ---------------- BN stats stage 2: reduce partials, produce scale/shift ----------------
__global__ __launch_bounds__(256) void finalize_stats2(
    const float* __restrict__ partials, const float* __restrict__ gamma,
    const float* __restrict__ beta, float* __restrict__ ss, float invN, int nb) {
  const int t = threadIdx.x;  // 256
  float s = 0.f;
#pragma unroll 8
  for (int b = 0; b < nb; ++b) s += partials[(size_t)b * 256 + t];
  __shared__ float tot[256];
  tot[t] = s;
  __syncthreads();
  if (t < 128) {
    float mean = tot[t] * invN;
    float var = tot[128 + t] * invN - mean * mean;
    float inv = rsqrtf(var + 1e-5f);
    float sc = gamma[t] * inv;
    ss[t] = sc;
    ss[128 + t] = beta[t] - mean * sc;
  }
}

__global__ __launch_bounds__(256) void bn_apply(
    float* __restrict__ out, const float* __restrict__ ss, int total4) {
  int idx = blockIdx.x * 256 + threadIdx.x;
  if (idx >= total4) return;
  int f4 = (idx & 31) * 4;
  float4 v = *(float4*)&out[(size_t)idx * 4];
  float4 sc = *(const float4*)&ss[f4];
  float4 sh = *(const float4*)&ss[128 + f4];
  v.x = fmaf(v.x, sc.x, sh.x);
  v.y = fmaf(v.y, sc.y, sh.y);
  v.z = fmaf(v.z, sc.z, sh.z);
  v.w = fmaf(v.w, sc.w, sh.w);
  *(float4*)&out[(size_t)idx * 4] = v;
}

// ---------------- launch ----------------
// ws layout (bytes):
//   [0,       65536)    Hpk bf16 fragments [2][2][4][8][64][8]
//   [65536,   66560)    ss: scale[128], shift[128]
//   [66560,   590848)   partials: NB_STATS x 256 floats
//   [590848,  791552)   rowptr (N+1 ints, padded)
//   [791552,  ...)      out2 bf16 [N*128]
extern "C" void kernel_launch(void* const* d_in, const int* in_sizes, int n_in,
                              void* d_out, int out_size, void* d_ws, size_t ws_size,
                              hipStream_t stream) {
  (void)n_in; (void)out_size; (void)ws_size;
  const float* input  = (const float*)d_in[0];
  const int*  adj_row = (const int*)d_in[1];
  const int*  adj_col = (const int*)d_in[2];
  const float* adj_val = (const float*)d_in[3];
  const float* w1 = (const float*)d_in[4];
  const float* w2 = (const float*)d_in[5];
  const float* gamma = (const float*)d_in[6];
  const float* beta  = (const float*)d_in[7];
  const int N = in_sizes[0] / F;
  const int E = in_sizes[1];

  char* ws = (char*)d_ws;
  short* Hpk = (short*)(ws);
  float* ss = (float*)(ws + 65536);
  float* partials = (float*)(ws + 66560);
  int* rowptr = (int*)(ws + 590848);
  short* out2b = (short*)(ws + 791552);
  float* agg = (float*)d_out;

  setup_kernel<<<16 + (E + 255) / 256, 256, 0, stream>>>(w1, w2, Hpk, adj_row, rowptr, E, N);
  gemm_mfma<<<(N + 127) / 128, 256, 0, stream>>>(input, Hpk, out2b, N);
  agg_rows3<<<(N * 64 + 255) / 256, 256, 0, stream>>>(
      (const uint32_t*)out2b, rowptr, adj_col, adj_val, agg, N);
  reduce_stats<<<NB_STATS, 256, 0, stream>>>(agg, partials, N);
  finalize_stats2<<<1, 256, 0, stream>>>(partials, gamma, beta, ss, 1.0f / (float)N, NB_STATS);
  bn_apply<<<(N * 32 + 255) / 256, 256, 0, stream>>>(agg, ss, N * 32);
}

// Round 8
// 90.474 us; speedup vs baseline: 3.5666x; 1.1896x over previous
//
#include <hip/hip_runtime.h>
#include <cstddef>
#include <cstdint>

#define F 128
#define LDK 136  // hid LDS row stride in shorts (272B, 16B aligned)
#define AGG_BLOCKS 2048
#define MID_BLOCKS 64

typedef __attribute__((ext_vector_type(8))) short short8;
typedef __attribute__((ext_vector_type(4))) float f32x4;

__device__ __forceinline__ short f2bf(float f) {
  uint32_t u = __float_as_uint(f);
  uint32_t r = u + 0x7FFFu + ((u >> 16) & 1u);  // round-to-nearest-even
  return (short)(r >> 16);
}
__device__ __forceinline__ float bf2f(short h) {
  return __uint_as_float(((uint32_t)(uint16_t)h) << 16);
}

// ---------------- setup: Hamilton pack (blocks 0..15) + CSR rowptr (rest) ----------------
// H[row][col] = sign * w[row&31][( (row>>5)^(col>>5) )*32 + (col&31)], neg mask 0x284E
// Hpk layout: [m(2)][part(2: hi,lo)][kt(4)][ct(8)][lane(64)][j(8)]  (128 KB total)
// B-frag: lane l, elem j  <->  B[kt*32 + (l>>4)*8 + j][ct*16 + (l&15)]
__global__ __launch_bounds__(256) void setup_kernel(
    const float* __restrict__ w1, const float* __restrict__ w2,
    short* __restrict__ Hpk, const int* __restrict__ adj_row,
    int* __restrict__ rowptr, int E, int N) {
  if (blockIdx.x < 16) {
    int idx = blockIdx.x * 256 + threadIdx.x;  // 4096: (m,kt,ct,lane)
    int m = idx >> 11;
    int kt = (idx >> 9) & 3;
    int ct = (idx >> 6) & 7;
    int l = idx & 63;
    int col = ct * 16 + (l & 15);
    const float* w = m ? w2 : w1;
    short hi[8], lo[8];
#pragma unroll
    for (int j = 0; j < 8; ++j) {
      int row = kt * 32 + (l >> 4) * 8 + j;  // k index of B
      int rb = row >> 5, cb = col >> 5;
      int neg = (0x284E >> (cb * 4 + rb)) & 1;
      float v = w[(row & 31) * 128 + (rb ^ cb) * 32 + (col & 31)];
      v = neg ? -v : v;
      short h = f2bf(v);
      hi[j] = h;
      lo[j] = f2bf(v - bf2f(h));
    }
    size_t b0 = ((((size_t)m * 2 + 0) * 4 + kt) * 8 + ct) * 64 + l;
    size_t b1 = ((((size_t)m * 2 + 1) * 4 + kt) * 8 + ct) * 64 + l;
    *(short8*)&Hpk[b0 * 8] = *(short8*)hi;
    *(short8*)&Hpk[b1 * 8] = *(short8*)lo;
  } else {
    int e = (blockIdx.x - 16) * 256 + threadIdx.x;
    if (e >= E) return;
    int r = adj_row[e];
    int rprev = (e == 0) ? -1 : adj_row[e - 1];
    for (int q = rprev + 1; q <= r; ++q) rowptr[q] = e;
    if (e == E - 1) {
      for (int q = r + 1; q <= N; ++q) rowptr[q] = E;
    }
  }
}

// ---------------- fused MFMA GEMM: out2 = tanh(X @ H1) @ H2, bf16 out ----------------
// 16 rows/wave, A-hi only, B hi+lo (2 mfma/tile), row-major hid in per-wave LDS.
__global__ __launch_bounds__(256) void gemm_mfma(
    const float* __restrict__ input, const short* __restrict__ Hpk,
    short* __restrict__ out2b, int N) {
  __shared__ short lds[4][16 * LDK];  // per-wave hid tile (17.4 KB/block)
  const int t = threadIdx.x;
  const int w = t >> 6, l = t & 63;
  const int lr = l & 15, lg = l >> 4;
  const int grow0 = blockIdx.x * 64 + w * 16;
  short* hid = &lds[w][0];

  // A1 fragments (hi only) from global f32
  short8 a1h[4];
  {
    int arow = grow0 + lr;
    if (arow >= N) arow = N - 1;
    const float* xr = &input[(size_t)arow * F];
#pragma unroll
    for (int kt = 0; kt < 4; ++kt) {
      float xv[8];
      *(float4*)&xv[0] = *(const float4*)&xr[kt * 32 + lg * 8];
      *(float4*)&xv[4] = *(const float4*)&xr[kt * 32 + lg * 8 + 4];
#pragma unroll
      for (int j = 0; j < 8; ++j) ((short*)&a1h[kt])[j] = f2bf(xv[j]);
    }
  }

  // GEMM1: acc = X @ H1
  f32x4 acc[8];
#pragma unroll
  for (int ct = 0; ct < 8; ++ct) acc[ct] = (f32x4){0.f, 0.f, 0.f, 0.f};
#pragma unroll
  for (int kt = 0; kt < 4; ++kt) {
#pragma unroll
    for (int ct = 0; ct < 8; ++ct) {
      short8 bh = *(const short8*)&Hpk[((((size_t)0 * 4 + kt) * 8 + ct) * 64 + l) * 8];
      short8 bl = *(const short8*)&Hpk[((((size_t)1 * 4 + kt) * 8 + ct) * 64 + l) * 8];
      acc[ct] = __builtin_amdgcn_mfma_f32_16x16x32_bf16(a1h[kt], bl, acc[ct], 0, 0, 0);
      acc[ct] = __builtin_amdgcn_mfma_f32_16x16x32_bf16(a1h[kt], bh, acc[ct], 0, 0, 0);
    }
  }

  // hid = tanh(acc) -> LDS row-major (C layout: row=lg*4+r, col=ct*16+lr)
#pragma unroll
  for (int ct = 0; ct < 8; ++ct)
#pragma unroll
    for (int r = 0; r < 4; ++r)
      hid[(lg * 4 + r) * LDK + ct * 16 + lr] = f2bf(tanhf(acc[ct][r]));

  // A2 fragments: vectorized b128 reads (row=lr, k contiguous)
  short8 a2h[4];
#pragma unroll
  for (int kt = 0; kt < 4; ++kt)
    a2h[kt] = *(short8*)&hid[lr * LDK + kt * 32 + lg * 8];

  // GEMM2: acc = hid @ H2
#pragma unroll
  for (int ct = 0; ct < 8; ++ct) acc[ct] = (f32x4){0.f, 0.f, 0.f, 0.f};
#pragma unroll
  for (int kt = 0; kt < 4; ++kt) {
#pragma unroll
    for (int ct = 0; ct < 8; ++ct) {
      short8 bh = *(const short8*)&Hpk[((((size_t)2 * 4 + kt) * 8 + ct) * 64 + l) * 8];
      short8 bl = *(const short8*)&Hpk[((((size_t)3 * 4 + kt) * 8 + ct) * 64 + l) * 8];
      acc[ct] = __builtin_amdgcn_mfma_f32_16x16x32_bf16(a2h[kt], bl, acc[ct], 0, 0, 0);
      acc[ct] = __builtin_amdgcn_mfma_f32_16x16x32_bf16(a2h[kt], bh, acc[ct], 0, 0, 0);
    }
  }

  // epilogue: bf16 pack -> LDS (reuse hid), then coalesced row stores
#pragma unroll
  for (int ct = 0; ct < 8; ++ct)
#pragma unroll
    for (int r = 0; r < 4; ++r)
      hid[(lg * 4 + r) * LDK + ct * 16 + lr] = f2bf(acc[ct][r]);
#pragma unroll
  for (int i = 0; i < 4; ++i) {
    int chunk = i * 64 + l;
    int row = chunk >> 4, pos = chunk & 15;
    int grow = grow0 + row;
    if (grow < N)
      *(short8*)&out2b[(size_t)grow * F + pos * 8] = *(short8*)&hid[row * LDK + pos * 8];
  }
}

// ---------------- segment-sum SpMM + fused BN stats ----------------
// grid-stride wave/row; 16 lanes/edge dwordx4 gather; per-block sum/sumsq partials.
__global__ __launch_bounds__(256) void agg_rows4(
    const uint32_t* __restrict__ out2u,  // N x 64 uints (bf16 pairs)
    const int* __restrict__ rowptr, const int* __restrict__ adj_col,
    const float* __restrict__ adj_val, float* __restrict__ agg,
    float* __restrict__ partials, int N) {
  const int t = threadIdx.x;
  const int w = t >> 6, lane = t & 63;
  const int sub = lane >> 4;   // which edge within a quad
  const int fl = lane & 15;    // 16B feature chunk (8 bf16 feats)
  const int wid = blockIdx.x * 4 + w;
  const int nw = gridDim.x * 4;
  float ssum[8], ssq[8];
#pragma unroll
  for (int j = 0; j < 8; ++j) { ssum[j] = 0.f; ssq[j] = 0.f; }

  for (int r = wid; r < N; r += nw) {
    const int row = __builtin_amdgcn_readfirstlane(r);
    const int start = rowptr[row];
    const int end = rowptr[row + 1];
    float acc[8];
#pragma unroll
    for (int j = 0; j < 8; ++j) acc[j] = 0.f;

    int e = start;
    for (; e + 16 <= end; e += 16) {
      int c[4]; float v[4]; uint4 u[4];
#pragma unroll
      for (int q = 0; q < 4; ++q) {
        int ee = e + q * 4 + sub;
        c[q] = adj_col[ee];
        v[q] = adj_val[ee];
      }
#pragma unroll
      for (int q = 0; q < 4; ++q)
        u[q] = *(const uint4*)&out2u[(size_t)c[q] * 64 + fl * 4];
#pragma unroll
      for (int q = 0; q < 4; ++q) {
#pragma unroll
        for (int k = 0; k < 4; ++k) {
          uint32_t uu = ((const uint32_t*)&u[q])[k];
          acc[2 * k]     = fmaf(v[q], __uint_as_float(uu << 16), acc[2 * k]);
          acc[2 * k + 1] = fmaf(v[q], __uint_as_float(uu & 0xFFFF0000u), acc[2 * k + 1]);
        }
      }
    }
    for (; e < end; e += 4) {
      int ee = e + sub;
      bool valid = ee < end;
      int c0 = adj_col[valid ? ee : end - 1];
      float v0 = valid ? adj_val[ee] : 0.f;
      uint4 u = *(const uint4*)&out2u[(size_t)c0 * 64 + fl * 4];
#pragma unroll
      for (int k = 0; k < 4; ++k) {
        uint32_t uu = ((const uint32_t*)&u)[k];
        acc[2 * k]     = fmaf(v0, __uint_as_float(uu << 16), acc[2 * k]);
        acc[2 * k + 1] = fmaf(v0, __uint_as_float(uu & 0xFFFF0000u), acc[2 * k + 1]);
      }
    }
    // fold the 4 edge-subgroups (all lanes end with full sums)
#pragma unroll
    for (int j = 0; j < 8; ++j) {
      acc[j] += __shfl_xor(acc[j], 16, 64);
      acc[j] += __shfl_xor(acc[j], 32, 64);
    }
    if (sub == 0) {
      *(float4*)&agg[(size_t)row * F + fl * 8] = make_float4(acc[0], acc[1], acc[2], acc[3]);
      *(float4*)&agg[(size_t)row * F + fl * 8 + 4] = make_float4(acc[4], acc[5], acc[6], acc[7]);
#pragma unroll
      for (int j = 0; j < 8; ++j) {
        ssum[j] += acc[j];
        ssq[j] = fmaf(acc[j], acc[j], ssq[j]);
      }
    }
  }

  // block-level stats reduce -> partials[block][256]
  __shared__ float ls[4][128];
  __shared__ float lq[4][128];
  if (sub == 0) {
#pragma unroll
    for (int j = 0; j < 8; ++j) {
      ls[w][fl * 8 + j] = ssum[j];
      lq[w][fl * 8 + j] = ssq[j];
    }
  }
  __syncthreads();
  if (t < 128) {
    float S = ls[0][t] + ls[1][t] + ls[2][t] + ls[3][t];
    float Q = lq[0][t] + lq[1][t] + lq[2][t] + lq[3][t];
    float* dst = &partials[(size_t)blockIdx.x * 256];
    dst[t] = S;
    dst[128 + t] = Q;
  }
}

// ---------------- stats mid-reduce: AGG_BLOCKS slices -> MID_BLOCKS slices ----------------
__global__ __launch_bounds__(256) void mid_reduce(
    const float* __restrict__ partials, float* __restrict__ mid, int nb) {
  const int k = blockIdx.x, t = threadIdx.x;
  const int per = nb / MID_BLOCKS;
  float s = 0.f;
#pragma unroll 4
  for (int i = 0; i < per; ++i)
    s += partials[(size_t)(k * per + i) * 256 + t];
  mid[(size_t)k * 256 + t] = s;
}

// ---------------- finalize: reduce mid, produce scale/shift ----------------
__global__ __launch_bounds__(256) void finalize_stats3(
    const float* __restrict__ mid, const float* __restrict__ gamma,
    const float* __restrict__ beta, float* __restrict__ ss, float invN) {
  const int t = threadIdx.x;  // 256
  float s = 0.f;
#pragma unroll 8
  for (int b = 0; b < MID_BLOCKS; ++b) s += mid[(size_t)b * 256 + t];
  __shared__ float tot[256];
  tot[t] = s;
  __syncthreads();
  if (t < 128) {
    float mean = tot[t] * invN;
    float var = tot[128 + t] * invN - mean * mean;
    float inv = rsqrtf(var + 1e-5f);
    float sc = gamma[t] * inv;
    ss[t] = sc;
    ss[128 + t] = beta[t] - mean * sc;
  }
}

__global__ __launch_bounds__(256) void bn_apply(
    float* __restrict__ out, const float* __restrict__ ss, int total4) {
  int idx = blockIdx.x * 256 + threadIdx.x;
  if (idx >= total4) return;
  int f4 = (idx & 31) * 4;
  float4 v = *(float4*)&out[(size_t)idx * 4];
  float4 sc = *(const float4*)&ss[f4];
  float4 sh = *(const float4*)&ss[128 + f4];
  v.x = fmaf(v.x, sc.x, sh.x);
  v.y = fmaf(v.y, sc.y, sh.y);
  v.z = fmaf(v.z, sc.z, sh.z);
  v.w = fmaf(v.w, sc.w, sh.w);
  *(float4*)&out[(size_t)idx * 4] = v;
}

// ---------------- launch ----------------
// ws layout (bytes):
//   [0,        131072)   Hpk bf16 fragments [2][2][4][8][64][8]  (128 KB!)
//   [131072,   132096)   ss: scale[128], shift[128]
//   [132096,   2229248)  partials: AGG_BLOCKS x 256 floats (2 MB)
//   [2229248,  2294784)  mid: MID_BLOCKS x 256 floats
//   [2294784,  2499584)  rowptr (N+1 ints, padded)
//   [2499584,  ...)      out2 bf16 [N*128] (12.8 MB)
extern "C" void kernel_launch(void* const* d_in, const int* in_sizes, int n_in,
                              void* d_out, int out_size, void* d_ws, size_t ws_size,
                              hipStream_t stream) {
  (void)n_in; (void)out_size; (void)ws_size;
  const float* input  = (const float*)d_in[0];
  const int*  adj_row = (const int*)d_in[1];
  const int*  adj_col = (const int*)d_in[2];
  const float* adj_val = (const float*)d_in[3];
  const float* w1 = (const float*)d_in[4];
  const float* w2 = (const float*)d_in[5];
  const float* gamma = (const float*)d_in[6];
  const float* beta  = (const float*)d_in[7];
  const int N = in_sizes[0] / F;
  const int E = in_sizes[1];

  char* ws = (char*)d_ws;
  short* Hpk = (short*)(ws);
  float* ss = (float*)(ws + 131072);
  float* partials = (float*)(ws + 132096);
  float* mid = (float*)(ws + 2229248);
  int* rowptr = (int*)(ws + 2294784);
  short* out2b = (short*)(ws + 2499584);
  float* agg = (float*)d_out;

  setup_kernel<<<16 + (E + 255) / 256, 256, 0, stream>>>(w1, w2, Hpk, adj_row, rowptr, E, N);
  gemm_mfma<<<(N + 63) / 64, 256, 0, stream>>>(input, Hpk, out2b, N);
  agg_rows4<<<AGG_BLOCKS, 256, 0, stream>>>(
      (const uint32_t*)out2b, rowptr, adj_col, adj_val, agg, partials, N);
  mid_reduce<<<MID_BLOCKS, 256, 0, stream>>>(partials, mid, AGG_BLOCKS);
  finalize_stats3<<<1, 256, 0, stream>>>(mid, gamma, beta, ss, 1.0f / (float)N);
  bn_apply<<<(N * 32 + 255) / 256, 256, 0, stream>>>(agg, ss, N * 32);
}

// Round 9
// 86.042 us; speedup vs baseline: 3.7503x; 1.0515x over previous
//
#include <hip/hip_runtime.h>
#include <cstddef>
#include <cstdint>

#define F 128
#define LDK 136  // hid LDS row stride in shorts (272B, 16B aligned)
#define AGG_BLOCKS 2048
#define MID_BLOCKS 64

typedef __attribute__((ext_vector_type(8))) short short8;
typedef __attribute__((ext_vector_type(4))) float f32x4;

__device__ __forceinline__ short f2bf(float f) {
  uint32_t u = __float_as_uint(f);
  uint32_t r = u + 0x7FFFu + ((u >> 16) & 1u);  // round-to-nearest-even
  return (short)(r >> 16);
}
__device__ __forceinline__ float bf2f(short h) {
  return __uint_as_float(((uint32_t)(uint16_t)h) << 16);
}

// ---------------- setup: Hamilton pack (blocks 0..15) + CSR rowptr (rest) ----------------
// H[row][col] = sign * w[row&31][( (row>>5)^(col>>5) )*32 + (col&31)], neg mask 0x284E
// Hpk layout: [m(2)][part(2: hi,lo)][kt(4)][ct(8)][lane(64)][j(8)]  (128 KB total)
// B-frag: lane l, elem j  <->  B[kt*32 + (l>>4)*8 + j][ct*16 + (l&15)]
__global__ __launch_bounds__(256) void setup_kernel(
    const float* __restrict__ w1, const float* __restrict__ w2,
    short* __restrict__ Hpk, const int* __restrict__ adj_row,
    int* __restrict__ rowptr, int E, int N) {
  if (blockIdx.x < 16) {
    int idx = blockIdx.x * 256 + threadIdx.x;  // 4096: (m,kt,ct,lane)
    int m = idx >> 11;
    int kt = (idx >> 9) & 3;
    int ct = (idx >> 6) & 7;
    int l = idx & 63;
    int col = ct * 16 + (l & 15);
    const float* w = m ? w2 : w1;
    short hi[8], lo[8];
#pragma unroll
    for (int j = 0; j < 8; ++j) {
      int row = kt * 32 + (l >> 4) * 8 + j;  // k index of B
      int rb = row >> 5, cb = col >> 5;
      int neg = (0x284E >> (cb * 4 + rb)) & 1;
      float v = w[(row & 31) * 128 + (rb ^ cb) * 32 + (col & 31)];
      v = neg ? -v : v;
      short h = f2bf(v);
      hi[j] = h;
      lo[j] = f2bf(v - bf2f(h));
    }
    size_t b0 = ((((size_t)m * 2 + 0) * 4 + kt) * 8 + ct) * 64 + l;
    size_t b1 = ((((size_t)m * 2 + 1) * 4 + kt) * 8 + ct) * 64 + l;
    *(short8*)&Hpk[b0 * 8] = *(short8*)hi;
    *(short8*)&Hpk[b1 * 8] = *(short8*)lo;
  } else {
    int e = (blockIdx.x - 16) * 256 + threadIdx.x;
    if (e >= E) return;
    int r = adj_row[e];
    int rprev = (e == 0) ? -1 : adj_row[e - 1];
    for (int q = rprev + 1; q <= r; ++q) rowptr[q] = e;
    if (e == E - 1) {
      for (int q = r + 1; q <= N; ++q) rowptr[q] = E;
    }
  }
}

// ---------------- fused MFMA GEMM: out2 = tanh(X @ H1) @ H2, bf16 out ----------------
// 16 rows/wave, A-hi only, B hi+lo (2 mfma/tile), row-major hid in per-wave LDS.
__global__ __launch_bounds__(256) void gemm_mfma(
    const float* __restrict__ input, const short* __restrict__ Hpk,
    short* __restrict__ out2b, int N) {
  __shared__ short lds[4][16 * LDK];  // per-wave hid tile (17.4 KB/block)
  const int t = threadIdx.x;
  const int w = t >> 6, l = t & 63;
  const int lr = l & 15, lg = l >> 4;
  const int grow0 = blockIdx.x * 64 + w * 16;
  short* hid = &lds[w][0];

  // A1 fragments (hi only) from global f32
  short8 a1h[4];
  {
    int arow = grow0 + lr;
    if (arow >= N) arow = N - 1;
    const float* xr = &input[(size_t)arow * F];
#pragma unroll
    for (int kt = 0; kt < 4; ++kt) {
      float xv[8];
      *(float4*)&xv[0] = *(const float4*)&xr[kt * 32 + lg * 8];
      *(float4*)&xv[4] = *(const float4*)&xr[kt * 32 + lg * 8 + 4];
#pragma unroll
      for (int j = 0; j < 8; ++j) ((short*)&a1h[kt])[j] = f2bf(xv[j]);
    }
  }

  // GEMM1: acc = X @ H1
  f32x4 acc[8];
#pragma unroll
  for (int ct = 0; ct < 8; ++ct) acc[ct] = (f32x4){0.f, 0.f, 0.f, 0.f};
#pragma unroll
  for (int kt = 0; kt < 4; ++kt) {
#pragma unroll
    for (int ct = 0; ct < 8; ++ct) {
      short8 bh = *(const short8*)&Hpk[((((size_t)0 * 4 + kt) * 8 + ct) * 64 + l) * 8];
      short8 bl = *(const short8*)&Hpk[((((size_t)1 * 4 + kt) * 8 + ct) * 64 + l) * 8];
      acc[ct] = __builtin_amdgcn_mfma_f32_16x16x32_bf16(a1h[kt], bl, acc[ct], 0, 0, 0);
      acc[ct] = __builtin_amdgcn_mfma_f32_16x16x32_bf16(a1h[kt], bh, acc[ct], 0, 0, 0);
    }
  }

  // hid = tanh(acc) -> LDS row-major (C layout: row=lg*4+r, col=ct*16+lr)
#pragma unroll
  for (int ct = 0; ct < 8; ++ct)
#pragma unroll
    for (int r = 0; r < 4; ++r)
      hid[(lg * 4 + r) * LDK + ct * 16 + lr] = f2bf(tanhf(acc[ct][r]));

  // A2 fragments: vectorized b128 reads (row=lr, k contiguous)
  short8 a2h[4];
#pragma unroll
  for (int kt = 0; kt < 4; ++kt)
    a2h[kt] = *(short8*)&hid[lr * LDK + kt * 32 + lg * 8];

  // GEMM2: acc = hid @ H2
#pragma unroll
  for (int ct = 0; ct < 8; ++ct) acc[ct] = (f32x4){0.f, 0.f, 0.f, 0.f};
#pragma unroll
  for (int kt = 0; kt < 4; ++kt) {
#pragma unroll
    for (int ct = 0; ct < 8; ++ct) {
      short8 bh = *(const short8*)&Hpk[((((size_t)2 * 4 + kt) * 8 + ct) * 64 + l) * 8];
      short8 bl = *(const short8*)&Hpk[((((size_t)3 * 4 + kt) * 8 + ct) * 64 + l) * 8];
      acc[ct] = __builtin_amdgcn_mfma_f32_16x16x32_bf16(a2h[kt], bl, acc[ct], 0, 0, 0);
      acc[ct] = __builtin_amdgcn_mfma_f32_16x16x32_bf16(a2h[kt], bh, acc[ct], 0, 0, 0);
    }
  }

  // epilogue: bf16 pack -> LDS (reuse hid), then coalesced row stores
#pragma unroll
  for (int ct = 0; ct < 8; ++ct)
#pragma unroll
    for (int r = 0; r < 4; ++r)
      hid[(lg * 4 + r) * LDK + ct * 16 + lr] = f2bf(acc[ct][r]);
#pragma unroll
  for (int i = 0; i < 4; ++i) {
    int chunk = i * 64 + l;
    int row = chunk >> 4, pos = chunk & 15;
    int grow = grow0 + row;
    if (grow < N)
      *(short8*)&out2b[(size_t)grow * F + pos * 8] = *(short8*)&hid[row * LDK + pos * 8];
  }
}

// ---------------- segment-sum SpMM + fused BN stats ----------------
// grid-stride wave/row; 16 lanes/edge dwordx4 gather; always-batched clamped
// quads (4 gathers in flight even for short rows); next-row rowptr prefetch.
__global__ __launch_bounds__(256) void agg_rows5(
    const uint32_t* __restrict__ out2u,  // N x 64 uints (bf16 pairs)
    const int* __restrict__ rowptr, const int* __restrict__ adj_col,
    const float* __restrict__ adj_val, float* __restrict__ agg,
    float* __restrict__ partials, int N) {
  const int t = threadIdx.x;
  const int w = t >> 6, lane = t & 63;
  const int sub = lane >> 4;   // which edge within a quad
  const int fl = lane & 15;    // 16B feature chunk (8 bf16 feats)
  const int wid = blockIdx.x * 4 + w;
  const int nw = gridDim.x * 4;
  float ssum[8], ssq[8];
#pragma unroll
  for (int j = 0; j < 8; ++j) { ssum[j] = 0.f; ssq[j] = 0.f; }

  int r = wid;
  int start = 0, end = 0;
  if (r < N) {
    start = rowptr[r];
    end = rowptr[r + 1];
  }
  while (r < N) {
    const int rn = r + nw;
    int sn = 0, en = 0;
    if (rn < N) {  // prefetch next row's ptrs; hoisted above the edge loop
      sn = rowptr[rn];
      en = rowptr[rn + 1];
    }
    const int row = __builtin_amdgcn_readfirstlane(r);
    float acc[8];
#pragma unroll
    for (int j = 0; j < 8; ++j) acc[j] = 0.f;

    for (int e = start; e < end; e += 16) {
      int c[4]; float v[4]; uint4 u[4];
#pragma unroll
      for (int q = 0; q < 4; ++q) {
        int ee = e + q * 4 + sub;
        bool valid = ee < end;
        int idx = valid ? ee : (end - 1);
        c[q] = adj_col[idx];
        v[q] = valid ? adj_val[idx] : 0.f;
      }
#pragma unroll
      for (int q = 0; q < 4; ++q)
        u[q] = *(const uint4*)&out2u[(size_t)c[q] * 64 + fl * 4];
#pragma unroll
      for (int q = 0; q < 4; ++q) {
#pragma unroll
        for (int k = 0; k < 4; ++k) {
          uint32_t uu = ((const uint32_t*)&u[q])[k];
          acc[2 * k]     = fmaf(v[q], __uint_as_float(uu << 16), acc[2 * k]);
          acc[2 * k + 1] = fmaf(v[q], __uint_as_float(uu & 0xFFFF0000u), acc[2 * k + 1]);
        }
      }
    }
    // fold the 4 edge-subgroups
#pragma unroll
    for (int j = 0; j < 8; ++j) {
      acc[j] += __shfl_xor(acc[j], 16, 64);
      acc[j] += __shfl_xor(acc[j], 32, 64);
    }
    if (sub == 0) {
      *(float4*)&agg[(size_t)row * F + fl * 8] = make_float4(acc[0], acc[1], acc[2], acc[3]);
      *(float4*)&agg[(size_t)row * F + fl * 8 + 4] = make_float4(acc[4], acc[5], acc[6], acc[7]);
#pragma unroll
      for (int j = 0; j < 8; ++j) {
        ssum[j] += acc[j];
        ssq[j] = fmaf(acc[j], acc[j], ssq[j]);
      }
    }
    r = rn;
    start = sn;
    end = en;
  }

  // block-level stats reduce -> partials[block][256]
  __shared__ float ls[4][128];
  __shared__ float lq[4][128];
  if (sub == 0) {
#pragma unroll
    for (int j = 0; j < 8; ++j) {
      ls[w][fl * 8 + j] = ssum[j];
      lq[w][fl * 8 + j] = ssq[j];
    }
  }
  __syncthreads();
  if (t < 128) {
    float S = ls[0][t] + ls[1][t] + ls[2][t] + ls[3][t];
    float Q = lq[0][t] + lq[1][t] + lq[2][t] + lq[3][t];
    float* dst = &partials[(size_t)blockIdx.x * 256];
    dst[t] = S;
    dst[128 + t] = Q;
  }
}

// ---------------- stats mid-reduce: AGG_BLOCKS slices -> MID_BLOCKS slices ----------------
__global__ __launch_bounds__(256) void mid_reduce(
    const float* __restrict__ partials, float* __restrict__ mid, int nb) {
  const int k = blockIdx.x, t = threadIdx.x;
  const int per = nb / MID_BLOCKS;
  float s = 0.f;
#pragma unroll 4
  for (int i = 0; i < per; ++i)
    s += partials[(size_t)(k * per + i) * 256 + t];
  mid[(size_t)k * 256 + t] = s;
}

// ---------------- finalize: reduce mid, produce scale/shift ----------------
__global__ __launch_bounds__(256) void finalize_stats3(
    const float* __restrict__ mid, const float* __restrict__ gamma,
    const float* __restrict__ beta, float* __restrict__ ss, float invN) {
  const int t = threadIdx.x;  // 256
  float s = 0.f;
#pragma unroll 8
  for (int b = 0; b < MID_BLOCKS; ++b) s += mid[(size_t)b * 256 + t];
  __shared__ float tot[256];
  tot[t] = s;
  __syncthreads();
  if (t < 128) {
    float mean = tot[t] * invN;
    float var = tot[128 + t] * invN - mean * mean;
    float inv = rsqrtf(var + 1e-5f);
    float sc = gamma[t] * inv;
    ss[t] = sc;
    ss[128 + t] = beta[t] - mean * sc;
  }
}

__global__ __launch_bounds__(256) void bn_apply(
    float* __restrict__ out, const float* __restrict__ ss, int total4) {
  int idx = blockIdx.x * 256 + threadIdx.x;
  if (idx >= total4) return;
  int f4 = (idx & 31) * 4;
  float4 v = *(float4*)&out[(size_t)idx * 4];
  float4 sc = *(const float4*)&ss[f4];
  float4 sh = *(const float4*)&ss[128 + f4];
  v.x = fmaf(v.x, sc.x, sh.x);
  v.y = fmaf(v.y, sc.y, sh.y);
  v.z = fmaf(v.z, sc.z, sh.z);
  v.w = fmaf(v.w, sc.w, sh.w);
  *(float4*)&out[(size_t)idx * 4] = v;
}

// ---------------- launch ----------------
// ws layout (bytes):
//   [0,        131072)   Hpk bf16 fragments [2][2][4][8][64][8]  (128 KB)
//   [131072,   132096)   ss: scale[128], shift[128]
//   [132096,   2229248)  partials: AGG_BLOCKS x 256 floats (2 MB)
//   [2229248,  2294784)  mid: MID_BLOCKS x 256 floats
//   [2294784,  2499584)  rowptr (N+1 ints, padded)
//   [2499584,  ...)      out2 bf16 [N*128] (12.8 MB)
extern "C" void kernel_launch(void* const* d_in, const int* in_sizes, int n_in,
                              void* d_out, int out_size, void* d_ws, size_t ws_size,
                              hipStream_t stream) {
  (void)n_in; (void)out_size; (void)ws_size;
  const float* input  = (const float*)d_in[0];
  const int*  adj_row = (const int*)d_in[1];
  const int*  adj_col = (const int*)d_in[2];
  const float* adj_val = (const float*)d_in[3];
  const float* w1 = (const float*)d_in[4];
  const float* w2 = (const float*)d_in[5];
  const float* gamma = (const float*)d_in[6];
  const float* beta  = (const float*)d_in[7];
  const int N = in_sizes[0] / F;
  const int E = in_sizes[1];

  char* ws = (char*)d_ws;
  short* Hpk = (short*)(ws);
  float* ss = (float*)(ws + 131072);
  float* partials = (float*)(ws + 132096);
  float* mid = (float*)(ws + 2229248);
  int* rowptr = (int*)(ws + 2294784);
  short* out2b = (short*)(ws + 2499584);
  float* agg = (float*)d_out;

  setup_kernel<<<16 + (E + 255) / 256, 256, 0, stream>>>(w1, w2, Hpk, adj_row, rowptr, E, N);
  gemm_mfma<<<(N + 63) / 64, 256, 0, stream>>>(input, Hpk, out2b, N);
  agg_rows5<<<AGG_BLOCKS, 256, 0, stream>>>(
      (const uint32_t*)out2b, rowptr, adj_col, adj_val, agg, partials, N);
  mid_reduce<<<MID_BLOCKS, 256, 0, stream>>>(partials, mid, AGG_BLOCKS);
  finalize_stats3<<<1, 256, 0, stream>>>(mid, gamma, beta, ss, 1.0f / (float)N);
  bn_apply<<<(N * 32 + 255) / 256, 256, 0, stream>>>(agg, ss, N * 32);
}